// Round 12
// baseline (1015.505 us; speedup 1.0000x reference)
//
#include <hip/hip_runtime.h>
#include <math.h>

typedef unsigned short bf16_t;
using bf16x8 = __attribute__((ext_vector_type(8))) short;
using f32x4  = __attribute__((ext_vector_type(4))) float;

#define DEVFN static __device__ __forceinline__

DEVFN float b2f(bf16_t u){ unsigned v=((unsigned)u)<<16; float f; __builtin_memcpy(&f,&v,4); return f; }
DEVFN bf16_t f2b(float f){ unsigned u; __builtin_memcpy(&u,&f,4); u += 0x7fffu + ((u>>16)&1u); return (bf16_t)(u>>16); }
DEVFN unsigned encf(float f){ unsigned u=__float_as_uint(f); return (u&0x80000000u)? ~u : (u|0x80000000u); }
DEVFN float decf(unsigned e){ return __uint_as_float((e&0x80000000u)? (e^0x80000000u) : ~e); }

// erf via Abramowitz-Stegun 7.1.26, |abs err| <= 1.5e-7
DEVFN float erf_fast(float x){
  float ax = fabsf(x);
  float t = __builtin_amdgcn_rcpf(1.0f + 0.3275911f*ax);
  float y = t*(0.254829592f + t*(-0.284496736f + t*(1.421413741f
          + t*(-1.453152027f + t*1.061405429f))));
  float r = 1.0f - y*__expf(-ax*ax);
  return copysignf(r, x);
}

constexpr float DN_SCALE = 0.35355339059327373f;   // 64^-0.25
constexpr float RATIO    = 0.06131393394849658f;   // 266^-0.5
constexpr float KEPS     = 1e-4f;
#define MPAD 288   // 266 features padded to 9*32

#define GLOAD_LDS16(g, l) __builtin_amdgcn_global_load_lds( \
    (__attribute__((address_space(1))) void*)(g), \
    (__attribute__((address_space(3))) void*)(l), 16, 0, 0)

#define MFMA16(a,b,c) __builtin_amdgcn_mfma_f32_16x16x32_bf16(a,b,c,0,0,0)

// ------------------------------------------------ weight transpose + cast
__global__ __launch_bounds__(256)
void wt_cast(const float* __restrict__ W, bf16_t* __restrict__ Wt, int K, int N)
{
  __shared__ alignas(16) float ts[32][33];
  int t = threadIdx.x;
  int r = t>>3, c4 = (t&7)*4;
  int k0 = blockIdx.x*32, n0 = blockIdx.y*32;
  float4 v = *(const float4*)(W + (size_t)(k0+r)*N + n0 + c4);
  ts[r][c4+0]=v.x; ts[r][c4+1]=v.y; ts[r][c4+2]=v.z; ts[r][c4+3]=v.w;
  __syncthreads();
  ushort4 o;
  o.x = f2b(ts[c4+0][r]); o.y = f2b(ts[c4+1][r]);
  o.z = f2b(ts[c4+2][r]); o.w = f2b(ts[c4+3][r]);
  *(ushort4*)(Wt + (size_t)(n0+r)*K + k0 + c4) = o;
}

__global__ __launch_bounds__(256)
void concat_bias(const float* __restrict__ bq, const float* __restrict__ bk,
                 const float* __restrict__ bv, float* __restrict__ dst)
{
  int t = blockIdx.x*256 + threadIdx.x;
  if (t < 512) dst[t] = bq[t];
  else if (t < 1024) dst[t] = bk[t-512];
  else dst[t] = bv[t-1024];
}

__global__ void mx_init(unsigned* m){ if (threadIdx.x < 32) m[threadIdx.x] = 0u; }

__global__ void zero_out(float* o, long n){
  long i = (long)blockIdx.x*256 + threadIdx.x;
  if (i < n) o[i] = 0.f;
}

// pmb[m][64] bf16 = pm * dn, zero-padded rows 266..287
__global__ __launch_bounds__(256)
void pm_cast(const float* __restrict__ pm, bf16_t* __restrict__ pmb)
{
  int idx = blockIdx.x*256 + threadIdx.x;      // grid 72 -> 18432
  int r = idx>>6, c = idx&63;
  pmb[idx] = (r < 266) ? f2b(pm[r*64+c]*DN_SCALE) : (bf16_t)0;
}

// v transpose: qkv v-part -> vT[bh*64+d][4096]. grid (128, 64), block 256
__global__ __launch_bounds__(256)
void vt_trans(const bf16_t* __restrict__ qkv, bf16_t* __restrict__ vT)
{
  __shared__ ushort ts[32][36];
  int by = blockIdx.y;
  int bh = by>>1, dt = by&1, b = bh>>3, h = bh&7;
  int n0 = blockIdx.x*32;
  int t = threadIdx.x, r = t>>3, c4 = (t&7)*4;
  ushort4 v = *(const ushort4*)(qkv + ((size_t)b*4096 + n0 + r)*1536 + 1024 + h*64 + dt*32 + c4);
  ts[r][c4+0]=v.x; ts[r][c4+1]=v.y; ts[r][c4+2]=v.z; ts[r][c4+3]=v.w;
  __syncthreads();
  ushort4 o;
  o.x = ts[c4+0][r]; o.y = ts[c4+1][r]; o.z = ts[c4+2][r]; o.w = ts[c4+3][r];
  *(ushort4*)(vT + ((size_t)bh*64 + dt*32 + r)*4096 + n0 + c4) = o;
}

// ---------------------------------------------------------------- LayerNorm
__global__ __launch_bounds__(256)
void ln_kernel(const float* __restrict__ x, const float* __restrict__ g,
               const float* __restrict__ b, bf16_t* __restrict__ out)
{
  long row = blockIdx.x; int t = threadIdx.x;
  float4 v = ((const float4*)x)[row*256 + t];
  float s = v.x+v.y+v.z+v.w;
  #pragma unroll
  for (int o=32;o>0;o>>=1) s += __shfl_xor(s, o);
  __shared__ float r1[4], r2[4];
  if ((t&63)==0) r1[t>>6] = s;
  __syncthreads();
  float mu = (r1[0]+r1[1]+r1[2]+r1[3]) * (1.f/1024.f);
  float dx = v.x-mu, dy = v.y-mu, dz = v.z-mu, dw = v.w-mu;
  float ss = dx*dx+dy*dy+dz*dz+dw*dw;
  #pragma unroll
  for (int o=32;o>0;o>>=1) ss += __shfl_xor(ss, o);
  if ((t&63)==0) r2[t>>6] = ss;
  __syncthreads();
  float var = (r2[0]+r2[1]+r2[2]+r2[3]) * (1.f/1024.f);
  float rs = rsqrtf(var + 1e-5f);
  float4 gg = ((const float4*)g)[t], bb = ((const float4*)b)[t];
  ushort4 o4;
  o4.x = f2b(dx*rs*gg.x+bb.x); o4.y = f2b(dy*rs*gg.y+bb.y);
  o4.z = f2b(dz*rs*gg.z+bb.z); o4.w = f2b(dw*rs*gg.w+bb.w);
  ((ushort4*)out)[row*256+t] = o4;
}

// f32 -> bf16 cast, grid = rows (of 1024)
__global__ __launch_bounds__(256)
void cast_f32_bf16(const float* __restrict__ in, bf16_t* __restrict__ out)
{
  long i = (long)blockIdx.x*256 + threadIdx.x;
  float4 v = ((const float4*)in)[i];
  ushort4 o;
  o.x = f2b(v.x); o.y = f2b(v.y); o.z = f2b(v.z); o.w = f2b(v.w);
  ((ushort4*)out)[i] = o;
}

// ---------------------------------------------------------------- GEMM (bf16 MFMA)
// 128x128 tile, BK=32, 4 waves, double-buffered LDS (2-phase: stage tile t+1
// BEFORE computing tile t; one __syncthreads per step).  PROVEN OPTIMUM here:
// manual vmcnt/raw-barrier variants (coarse 256² 8-phase, 3-buf sched-pinned,
// depth-2 counted) all measured slower (R6/R8/R10).  XCD-bijective chunking +
// 16-row supertile block remap for L2 locality (requires nwg%8==0, Mtiles%16==0).
template<int RES, int GELU, int GATEF, int OBF>
__global__ __launch_bounds__(256)
void gemm_bt(const bf16_t* __restrict__ A, int lda,
             const bf16_t* __restrict__ Bt, int ldb,
             const float* __restrict__ bias,
             const float* res,
             const float* gatef,
             void* Cout, int N, int K)
{
  __shared__ alignas(16) bf16_t As[2][128*32];
  __shared__ alignas(16) bf16_t Bs[2][128*32];
  const int tid = threadIdx.x;
  const int wid = tid>>6, lane = tid&63;
  const int l15 = lane&15, l4 = lane>>4;
  const int wm = wid>>1, wn = wid&1;

  // ---- block remap: XCD-contiguous chunks over a ty-fast supertiled order
  const int NX = gridDim.x;
  const int nwg = NX * gridDim.y;
  const int lid = blockIdx.y*NX + blockIdx.x;
  const int qc = nwg>>3;
  const int wgid = (lid&7)*qc + (lid>>3);          // nwg%8==0 bijective chunk
  const int stripe = wgid / (16*NX);
  const int rem    = wgid % (16*NX);
  const long m0 = (long)(stripe*16 + (rem & 15))*128;
  const long n0 = (long)(rem >> 4)*128;

  f32x4 acc[4][4];
  #pragma unroll
  for (int i=0;i<4;i++)
    #pragma unroll
    for (int j=0;j<4;j++) acc[i][j] = f32x4{0.f,0.f,0.f,0.f};

  const bf16_t* ga = A  + (size_t)(m0 + (tid>>2))*lda + (tid&3)*8;
  const bf16_t* gb = Bt + (size_t)(n0 + (tid>>2))*ldb + (tid&3)*8;

  auto STAGE = [&](int buf){
    GLOAD_LDS16(ga,                   &As[buf][wid*512]);
    GLOAD_LDS16(ga + (size_t)64*lda,  &As[buf][2048 + wid*512]);
    GLOAD_LDS16(gb,                   &Bs[buf][wid*512]);
    GLOAD_LDS16(gb + (size_t)64*ldb,  &Bs[buf][2048 + wid*512]);
    ga += 32; gb += 32;
  };

  const int nt = K >> 5;
  STAGE(0);
  __syncthreads();                      // drains vmcnt(0): tile 0 resident
  int cur = 0;
  for (int t = 0; t < nt; ++t){
    if (t+1 < nt) STAGE(cur^1);         // issue next-tile loads FIRST
    bf16x8 af[4], bfr[4];
    #pragma unroll
    for (int i=0;i<4;i++){
      af[i]  = *(const bf16x8*)(&As[cur][(wm*64 + i*16 + l15)*32 + l4*8]);
      bfr[i] = *(const bf16x8*)(&Bs[cur][(wn*64 + i*16 + l15)*32 + l4*8]);
    }
    #pragma unroll
    for (int i=0;i<4;i++)
      #pragma unroll
      for (int j=0;j<4;j++)
        acc[i][j] = MFMA16(af[i], bfr[j], acc[i][j]);
    __syncthreads();                    // drains vmcnt(0): next tile resident,
    cur ^= 1;                           // and all reads of As[cur] complete
  }

  #pragma unroll
  for (int i=0;i<4;i++){
    #pragma unroll
    for (int j=0;j<4;j++){
      #pragma unroll
      for (int r=0;r<4;r++){
        long row = m0 + wm*64 + i*16 + l4*4 + r;
        long col = n0 + wn*64 + j*16 + l15;
        float v = acc[i][j][r] + bias[col];
        if constexpr (RES)   v += res[row*(long)N + col];
        if constexpr (GELU)  v = 0.5f*v*(1.0f + erf_fast(v*0.70710678118654752f));
        if constexpr (GATEF) v *= gatef[row*(long)N + col];
        if constexpr (OBF)  ((bf16_t*)Cout)[row*(long)N + col] = f2b(v);
        else                ((float* )Cout)[row*(long)N + col] = v;
      }
    }
  }
}

// ---------------------------------------------------------------- FAVOR (MFMA)
// qkv: [16384][1536] bf16, q @ h*64, k @ 512+h*64, v @ 1024+h*64.

// dd-max over all (n,m) per bh. grid (64, 32), block 256 (4 waves x 16 rows)
__global__ __launch_bounds__(256,2)
void favor_kmax2(const bf16_t* __restrict__ qkv, const bf16_t* __restrict__ pmb,
                 unsigned* __restrict__ mxk)
{
  int bh = blockIdx.y, b = bh>>3, h = bh&7;
  int t = threadIdx.x, wid = t>>6, lane = t&63;
  int l15 = lane&15, l4 = lane>>4;
  int n0 = blockIdx.x*64, row0 = wid*16;
  f32x4 acc[18];
  #pragma unroll
  for (int c=0;c<18;c++) acc[c] = f32x4{0.f,0.f,0.f,0.f};
  const bf16_t* abase = qkv + ((size_t)(b*4096) + n0 + row0 + l15)*1536 + 512 + h*64;
  #pragma unroll
  for (int kh=0;kh<2;kh++){
    bf16x8 a = *(const bf16x8*)(abase + kh*32 + l4*8);
    #pragma unroll
    for (int ct=0;ct<18;ct++){
      bf16x8 bb = *(const bf16x8*)(pmb + (ct*16+l15)*64 + kh*32 + l4*8);
      acc[ct] = MFMA16(a, bb, acc[ct]);
    }
  }
  float mx = -3e38f;
  #pragma unroll
  for (int ct=0;ct<18;ct++){
    if (ct*16 + l15 < 266){
      #pragma unroll
      for (int r=0;r<4;r++) mx = fmaxf(mx, acc[ct][r]);
    }
  }
  #pragma unroll
  for (int o=32;o>0;o>>=1) mx = fmaxf(mx, __shfl_xor(mx, o));
  __shared__ float red[4];
  if (lane==0) red[wid] = mx;
  __syncthreads();
  if (t==0){
    float m2 = fmaxf(fmaxf(red[0],red[1]),fmaxf(red[2],red[3]));
    atomicMax(mxk + bh, encf(m2));
  }
}

// kp = ratio*(exp(dd - diag - MX)+eps) written DIRECTLY transposed to
// kpT[bhl][MPAD m][4096 n]; diag computed in-kernel from the same fragments.
// grid (64, KG), block 256
__global__ __launch_bounds__(256,2)
void favor_kp(const bf16_t* __restrict__ qkv, const bf16_t* __restrict__ pmb,
              const unsigned* __restrict__ mxk, bf16_t* __restrict__ kpT, int bh0)
{
  int bhl = blockIdx.y, bh = bh0 + bhl, b = bh>>3, h = bh&7;
  int t = threadIdx.x, wid = t>>6, lane = t&63;
  int l15 = lane&15, l4 = lane>>4;
  int n0 = blockIdx.x*64, row0 = wid*16;
  f32x4 acc[18];
  #pragma unroll
  for (int c=0;c<18;c++) acc[c] = f32x4{0.f,0.f,0.f,0.f};
  const bf16_t* abase = qkv + ((size_t)(b*4096) + n0 + row0 + l15)*1536 + 512 + h*64;
  float rsq = 0.f;
  #pragma unroll
  for (int kh=0;kh<2;kh++){
    bf16x8 a = *(const bf16x8*)(abase + kh*32 + l4*8);
    #pragma unroll
    for (int e=0;e<8;e++){ float v = b2f((bf16_t)a[e]); rsq += v*v; }
    #pragma unroll
    for (int ct=0;ct<18;ct++){
      bf16x8 bb = *(const bf16x8*)(pmb + (ct*16+l15)*64 + kh*32 + l4*8);
      acc[ct] = MFMA16(a, bb, acc[ct]);
    }
  }
  rsq += __shfl_xor(rsq, 16);
  rsq += __shfl_xor(rsq, 32);                 // lanes sharing l15: full row sumsq
  float MX = decf(mxk[bh]);
  constexpr float DSC = 0.5f*DN_SCALE*DN_SCALE;
  float dg[4];
  #pragma unroll
  for (int r=0;r<4;r++) dg[r] = DSC * __shfl(rsq, l4*4 + r);
  #pragma unroll
  for (int ct=0;ct<18;ct++){
    int col = ct*16 + l15;
    ushort4 o;
    if (col < 266){
      o.x = f2b(RATIO*(__expf(acc[ct][0] - dg[0] - MX) + KEPS));
      o.y = f2b(RATIO*(__expf(acc[ct][1] - dg[1] - MX) + KEPS));
      o.z = f2b(RATIO*(__expf(acc[ct][2] - dg[2] - MX) + KEPS));
      o.w = f2b(RATIO*(__expf(acc[ct][3] - dg[3] - MX) + KEPS));
    } else { o.x=0; o.y=0; o.z=0; o.w=0; }
    *(ushort4*)(kpT + ((size_t)bhl*MPAD + col)*4096 + n0 + row0 + l4*4) = o;
  }
}

// ctx partial GEMM (K-split x4) with fused partial ksum. grid (17, 4, KG).
__global__ __launch_bounds__(256,2)
void ctx_gemm(const bf16_t* __restrict__ kpT, const bf16_t* __restrict__ vT,
              float* __restrict__ ctxP, float* __restrict__ ksumP, int bh0)
{
  int m0 = blockIdx.x*16, ks = blockIdx.y, bhl = blockIdx.z, bh = bh0 + bhl;
  int t = threadIdx.x, wid = t>>6, lane = t&63;
  int l15 = lane&15, l4 = lane>>4;
  f32x4 acc[4];
  #pragma unroll
  for (int c=0;c<4;c++) acc[c] = f32x4{0.f,0.f,0.f,0.f};
  const bf16_t* Abase = kpT + ((size_t)bhl*MPAD + m0 + l15)*4096;
  const bf16_t* Bbase = vT + ((size_t)bh*64)*4096;
  const int kb = ks*1024 + wid*256;
  float ksp = 0.f;
  for (int k = kb; k < kb + 256; k += 32){
    bf16x8 a = *(const bf16x8*)(Abase + k + l4*8);
    #pragma unroll
    for (int e=0;e<8;e++) ksp += b2f((bf16_t)a[e]);
    #pragma unroll
    for (int ct=0;ct<4;ct++){
      bf16x8 bb = *(const bf16x8*)(Bbase + (size_t)(ct*16+l15)*4096 + k + l4*8);
      acc[ct] = MFMA16(a, bb, acc[ct]);
    }
  }
  // row-sum partials: combine the 4 lanes sharing l15
  ksp += __shfl_xor(ksp, 16);
  ksp += __shfl_xor(ksp, 32);
  __shared__ float red[4][4][16][16];
  __shared__ float ksred[4][16];
  if (l4 == 0) ksred[wid][l15] = ksp;
  #pragma unroll
  for (int ct=0;ct<4;ct++)
    #pragma unroll
    for (int r=0;r<4;r++) red[wid][ct][l4*4+r][l15] = acc[ct][r];
  __syncthreads();
  #pragma unroll
  for (int i=0;i<4;i++){
    int e = i*256 + t;
    int ct = e>>8, row = (e>>4)&15, col = e&15;
    float s = ((red[0][ct][row][col] + red[1][ct][row][col])
             + (red[2][ct][row][col] + red[3][ct][row][col]));
    ctxP[(((size_t)bhl*4 + ks)*272 + m0 + row)*64 + ct*16 + col] = s;
  }
  if (t < 16){
    float s2 = ksred[0][t] + ksred[1][t] + ksred[2][t] + ksred[3][t];
    ksumP[((size_t)bhl*4 + ks)*272 + m0 + t] = s2;
  }
}

// reduce K-split partials -> ctxT[bh][d][MPAD m] bf16 (zero pad m>=272) and
// ksumf[bh][m].  grid (72, KG)
__global__ __launch_bounds__(256)
void ctx_reduce(const float* __restrict__ ctxP, const float* __restrict__ ksumP,
                bf16_t* __restrict__ ctxT, float* __restrict__ ksumf, int bh0)
{
  int bhl = blockIdx.y, bh = bh0 + bhl;
  int idx = blockIdx.x*256 + threadIdx.x;   // < 18432 = 288*64
  int m = idx>>6, d = idx&63;
  float s = 0.f;
  if (m < 272){
    #pragma unroll
    for (int ks=0;ks<4;ks++)
      s += ctxP[(((size_t)bhl*4 + ks)*272 + m)*64 + d];
  }
  ctxT[((size_t)bh*64 + d)*MPAD + m] = f2b(s);
  if (idx < 272){
    float s2 = 0.f;
    #pragma unroll
    for (int ks=0;ks<4;ks++)
      s2 += ksumP[(((size_t)bhl*4 + ks)*272) + idx];
    ksumf[(size_t)bh*MPAD + idx] = s2;
  }
}

// fused q-side: dd MFMA -> in-kernel diag -> rowmax -> qp -> LDS ->
// out MFMA * dinv -> attn. grid (64, 32), block 256
__global__ __launch_bounds__(256,2)
void favor_q(const bf16_t* __restrict__ qkv, const bf16_t* __restrict__ pmb,
             const float* __restrict__ ksumf,
             const bf16_t* __restrict__ ctxT, bf16_t* __restrict__ attn)
{
  __shared__ alignas(16) ushort qpLds[64*296];
  __shared__ float ksLds[288];
  int bh = blockIdx.y, b = bh>>3, h = bh&7;
  int t = threadIdx.x, wid = t>>6, lane = t&63;
  int l15 = lane&15, l4 = lane>>4;
  int n0 = blockIdx.x*64, row0 = wid*16;
  ksLds[t] = (t < 272) ? ksumf[(size_t)bh*MPAD + t] : 0.f;
  if (t < 32) ksLds[256+t] = (256+t < 272) ? ksumf[(size_t)bh*MPAD + 256 + t] : 0.f;
  __syncthreads();

  f32x4 acc[18];
  #pragma unroll
  for (int c=0;c<18;c++) acc[c] = f32x4{0.f,0.f,0.f,0.f};
  const bf16_t* abase = qkv + ((size_t)(b*4096) + n0 + row0 + l15)*1536 + h*64;
  float rsq = 0.f;
  #pragma unroll
  for (int kh=0;kh<2;kh++){
    bf16x8 a = *(const bf16x8*)(abase + kh*32 + l4*8);
    #pragma unroll
    for (int e=0;e<8;e++){ float v = b2f((bf16_t)a[e]); rsq += v*v; }
    #pragma unroll
    for (int ct=0;ct<18;ct++){
      bf16x8 bb = *(const bf16x8*)(pmb + (ct*16+l15)*64 + kh*32 + l4*8);
      acc[ct] = MFMA16(a, bb, acc[ct]);
    }
  }
  rsq += __shfl_xor(rsq, 16);
  rsq += __shfl_xor(rsq, 32);
  constexpr float DSC = 0.5f*DN_SCALE*DN_SCALE;
  float dg[4];
  #pragma unroll
  for (int r=0;r<4;r++) dg[r] = DSC * __shfl(rsq, l4*4 + r);

  // per-row max over valid cols
  float mxr[4] = {-3e38f,-3e38f,-3e38f,-3e38f};
  #pragma unroll
  for (int ct=0;ct<18;ct++){
    if (ct*16 + l15 < 266){
      #pragma unroll
      for (int r=0;r<4;r++) mxr[r] = fmaxf(mxr[r], acc[ct][r]);
    }
  }
  #pragma unroll
  for (int r=0;r<4;r++){
    mxr[r] = fmaxf(mxr[r], __shfl_xor(mxr[r], 1));
    mxr[r] = fmaxf(mxr[r], __shfl_xor(mxr[r], 2));
    mxr[r] = fmaxf(mxr[r], __shfl_xor(mxr[r], 4));
    mxr[r] = fmaxf(mxr[r], __shfl_xor(mxr[r], 8));
  }
  float den[4] = {0.f,0.f,0.f,0.f};
  #pragma unroll
  for (int ct=0;ct<18;ct++){
    int col = ct*16 + l15;
    float ks = ksLds[col];
    #pragma unroll
    for (int r=0;r<4;r++){
      float qpv = 0.f;
      if (col < 266){
        qpv = RATIO*(__expf(acc[ct][r] - dg[r] - mxr[r]) + KEPS);
        den[r] += qpv*ks;
      }
      qpLds[(row0 + l4*4 + r)*296 + col] = f2b(qpv);
    }
  }
  float dinv[4];
  #pragma unroll
  for (int r=0;r<4;r++){
    den[r] += __shfl_xor(den[r], 1);
    den[r] += __shfl_xor(den[r], 2);
    den[r] += __shfl_xor(den[r], 4);
    den[r] += __shfl_xor(den[r], 8);
    dinv[r] = 1.0f/den[r];
  }
  __syncthreads();

  f32x4 o2[4];
  #pragma unroll
  for (int c=0;c<4;c++) o2[c] = f32x4{0.f,0.f,0.f,0.f};
  const bf16_t* Bbase = ctxT + (size_t)bh*64*MPAD;
  #pragma unroll
  for (int kk=0;kk<9;kk++){
    int k0 = kk*32;
    bf16x8 a = *(const bf16x8*)&qpLds[(row0 + l15)*296 + k0 + l4*8];
    #pragma unroll
    for (int ct=0;ct<4;ct++){
      bf16x8 bb = *(const bf16x8*)(Bbase + (size_t)(ct*16+l15)*MPAD + k0 + l4*8);
      o2[ct] = MFMA16(a, bb, o2[ct]);
    }
  }
  #pragma unroll
  for (int ct=0;ct<4;ct++)
    #pragma unroll
    for (int r=0;r<4;r++)
      attn[((size_t)(b*4096) + n0 + row0 + l4*4 + r)*512 + h*64 + ct*16 + l15]
        = f2b(o2[ct][r] * dinv[r]);
}

// ---------------------------------------------------------------- launcher
extern "C" void kernel_launch(void* const* d_in, const int* in_sizes, int n_in,
                              void* d_out, int out_size, void* d_ws, size_t ws_size,
                              hipStream_t stream)
{
  (void)in_sizes; (void)n_in; (void)out_size;
  const float* x      = (const float*)d_in[0];
  const float* proj_w = (const float*)d_in[1];
  const float* proj_b = (const float*)d_in[2];
  const float* ln1_g  = (const float*)d_in[3];
  const float* ln1_b  = (const float*)d_in[4];
  const float* wq     = (const float*)d_in[5];
  const float* bq     = (const float*)d_in[6];
  const float* wk     = (const float*)d_in[7];
  const float* bk     = (const float*)d_in[8];
  const float* wv     = (const float*)d_in[9];
  const float* bv     = (const float*)d_in[10];
  const float* wo     = (const float*)d_in[11];
  const float* bo     = (const float*)d_in[12];
  const float* pm     = (const float*)d_in[13];
  const float* ln2_g  = (const float*)d_in[14];
  const float* ln2_b  = (const float*)d_in[15];
  const float* w1     = (const float*)d_in[16];
  const float* b1     = (const float*)d_in[17];
  const float* w2     = (const float*)d_in[18];
  const float* b2     = (const float*)d_in[19];
  float* out = (float*)d_out;
  const size_t MB = 1ull<<20;

  char* ws = (char*)d_ws;
  size_t off = 0;
  auto alloc = [&](size_t bytes)->void*{ void* p = ws + off; off += (bytes + 255) & ~(size_t)255; return p; };
  bf16_t* Wt_proj = (bf16_t*)alloc(2ul*1024*1024);
  bf16_t* Wt_qkv  = (bf16_t*)alloc(2ul*1536*1024);
  bf16_t* Wt_o    = (bf16_t*)alloc(2ul*1024*512);
  bf16_t* Wt_1    = (bf16_t*)alloc(2ul*4096*1024);
  bf16_t* Wt_2    = (bf16_t*)alloc(2ul*1024*4096);
  float*  bqkv    = (float*) alloc(4ul*1536);
  unsigned* mxk   = (unsigned*)alloc(4ul*32);
  bf16_t* pmb     = (bf16_t*)alloc(2ul*MPAD*64);
  float*  ksumf   = (float*) alloc(4ul*32*MPAD);
  bf16_t* ctxT    = (bf16_t*)alloc(2ul*32*64*MPAD);
  float*  ctxP    = (float*) alloc(4ul*32*4*272*64);  // K-split partials (KG<=32)
  float*  ksumP   = (float*) alloc(4ul*32*4*272);
  char*   R       = (char*)  alloc(0);
  size_t R_avail = (ws_size > off) ? ws_size - off : 0;

  // workspace tiers (fallbacks are the proven configs):
  //  T3: kside 48+75.5, ff 32+134  -> 167MB   KG=32 NC=1 ACH=16384
  //  T2: kside 123.5, phaseA/ff 80 -> 125MB   KG=32 NC=2 ACH=16384
  //  T1: ff 80, kside 67           ->  84MB   KG=8  NC=2 ACH=8192
  //  T0: phaseA 64, kside 57, ff 40->  67MB   KG=4  NC=4 ACH=8192
  int KG, NC; long ACH;
  if      (R_avail >= 167*MB){ KG = 32; NC = 1; ACH = 16384; }
  else if (R_avail >= 125*MB){ KG = 32; NC = 2; ACH = 16384; }
  else if (R_avail >=  84*MB){ KG = 8;  NC = 2; ACH = 8192;  }
  else if (R_avail >=  67*MB){ KG = 4;  NC = 4; ACH = 8192;  }
  else { zero_out<<<dim3(65536), 256, 0, stream>>>(out, 16777216L); return; }

  // R overlays (stream-serialized disjoint lifetimes)
  bf16_t* qkv  = (bf16_t*)(R);               // 48MB   [LN1/qkv .. favor_q]
  bf16_t* h1c  = (bf16_t*)(R + 48*MB);       // ACH*2KB [phase A]
  bf16_t* kpT  = (bf16_t*)(R + 48*MB);       // KG*2.36MB [k-side]
  bf16_t* attn = (bf16_t*)(R + 48*MB);       // 16MB   [favor_q .. wo]
  long    CH   = 16384/NC;
  bf16_t* h2c  = (bf16_t*)(R);               // CH*2KB [phase 5]
  bf16_t* ff1c = (bf16_t*)(R + (NC==1 ? 32 : 16)*MB);  // CH*8KB
  bf16_t* vT   = (bf16_t*)d_out;             // 16.8MB scratch in d_out (dead till wo)

  // 1) weights -> bf16 transposed, pm cast
  wt_cast<<<dim3(32,32), 256, 0, stream>>>(proj_w, Wt_proj, 1024, 1024);
  wt_cast<<<dim3(32,16), 256, 0, stream>>>(wq, Wt_qkv,              1024, 512);
  wt_cast<<<dim3(32,16), 256, 0, stream>>>(wk, Wt_qkv + 512*1024,   1024, 512);
  wt_cast<<<dim3(32,16), 256, 0, stream>>>(wv, Wt_qkv + 1024*1024,  1024, 512);
  wt_cast<<<dim3(16,32), 256, 0, stream>>>(wo, Wt_o, 512, 1024);
  wt_cast<<<dim3(32,128),256, 0, stream>>>(w1, Wt_1, 1024, 4096);
  wt_cast<<<dim3(128,32),256, 0, stream>>>(w2, Wt_2, 4096, 1024);
  concat_bias<<<dim3(6), 256, 0, stream>>>(bq, bk, bv, bqkv);
  pm_cast<<<dim3(72), 256, 0, stream>>>(pm, pmb);

  // 2) phase A: LN1 + qkv GEMM (single-shot when workspace allows)
  for (long c = 0; c < 16384/ACH; c++){
    ln_kernel<<<dim3((unsigned)ACH), 256, 0, stream>>>(x + (size_t)c*ACH*1024, ln1_g, ln1_b, h1c);
    gemm_bt<0,0,0,1><<<dim3(12,(unsigned)(ACH/128)), 256, 0, stream>>>(h1c, 1024, Wt_qkv, 1024,
        bqkv, nullptr, nullptr, qkv + (size_t)c*ACH*1536, 1536, 1024);
  }

  // 3) FAVOR
  vt_trans<<<dim3(128,64), 256, 0, stream>>>(qkv, vT);
  mx_init<<<dim3(1), 64, 0, stream>>>(mxk);
  favor_kmax2<<<dim3(64,32), 256, 0, stream>>>(qkv, pmb, mxk);
  for (int g = 0; g < 32; g += KG){
    favor_kp<<<dim3(64,KG), 256, 0, stream>>>(qkv, pmb, mxk, kpT, g);
    ctx_gemm<<<dim3(17,4,KG), 256, 0, stream>>>(kpT, vT, ctxP, ksumP, g);
    ctx_reduce<<<dim3(72,KG), 256, 0, stream>>>(ctxP, ksumP, ctxT, ksumf, g);
  }
  favor_q<<<dim3(64,32), 256, 0, stream>>>(qkv, pmb, ksumf, ctxT, attn);

  // 4) x2 = x + attn @ wo + bo -> d_out (f32); overwrites vT scratch
  gemm_bt<1,0,0,0><<<dim3(8,128), 256, 0, stream>>>(attn, 512, Wt_o, 512,
      bo, x, nullptr, out, 1024, 512);

  // 5) per chunk: LN2 -> ff1(gelu) -> ff2(+res, in-place) -> gate(in-place)
  for (int c = 0; c < NC; c++){
    float* xrow = out + (size_t)c*CH*1024;
    ln_kernel<<<dim3((unsigned)CH), 256, 0, stream>>>(xrow, ln2_g, ln2_b, h2c);
    gemm_bt<0,1,0,1><<<dim3(32,(unsigned)(CH/128)), 256, 0, stream>>>(h2c, 1024, Wt_1, 1024,
        b1, nullptr, nullptr, ff1c, 4096, 1024);
    gemm_bt<1,0,0,0><<<dim3(8,(unsigned)(CH/128)), 256, 0, stream>>>(ff1c, 4096, Wt_2, 4096,
        b2, xrow, nullptr, xrow, 1024, 4096);
    cast_f32_bf16<<<dim3((unsigned)CH), 256, 0, stream>>>(x + (size_t)c*CH*1024, h2c);
    gemm_bt<0,0,1,0><<<dim3(8,(unsigned)(CH/128)), 256, 0, stream>>>(h2c, 1024, Wt_proj, 1024,
        proj_b, nullptr, xrow, xrow, 1024, 1024);
  }
}

// Round 13
// 946.013 us; speedup vs baseline: 1.0735x; 1.0735x over previous
//
#include <hip/hip_runtime.h>
#include <math.h>

typedef unsigned short bf16_t;
using bf16x8 = __attribute__((ext_vector_type(8))) short;
using f32x4  = __attribute__((ext_vector_type(4))) float;

#define DEVFN static __device__ __forceinline__

DEVFN float b2f(bf16_t u){ unsigned v=((unsigned)u)<<16; float f; __builtin_memcpy(&f,&v,4); return f; }
DEVFN bf16_t f2b(float f){ unsigned u; __builtin_memcpy(&u,&f,4); u += 0x7fffu + ((u>>16)&1u); return (bf16_t)(u>>16); }
DEVFN unsigned encf(float f){ unsigned u=__float_as_uint(f); return (u&0x80000000u)? ~u : (u|0x80000000u); }
DEVFN float decf(unsigned e){ return __uint_as_float((e&0x80000000u)? (e^0x80000000u) : ~e); }

// erf via Abramowitz-Stegun 7.1.26, |abs err| <= 1.5e-7
DEVFN float erf_fast(float x){
  float ax = fabsf(x);
  float t = __builtin_amdgcn_rcpf(1.0f + 0.3275911f*ax);
  float y = t*(0.254829592f + t*(-0.284496736f + t*(1.421413741f
          + t*(-1.453152027f + t*1.061405429f))));
  float r = 1.0f - y*__expf(-ax*ax);
  return copysignf(r, x);
}

constexpr float DN_SCALE = 0.35355339059327373f;   // 64^-0.25
constexpr float RATIO    = 0.06131393394849658f;   // 266^-0.5
constexpr float KEPS     = 1e-4f;
#define MPAD 288   // 266 features padded to 9*32

#define GLOAD_LDS16(g, l) __builtin_amdgcn_global_load_lds( \
    (__attribute__((address_space(1))) void*)(g), \
    (__attribute__((address_space(3))) void*)(l), 16, 0, 0)

#define MFMA16(a,b,c) __builtin_amdgcn_mfma_f32_16x16x32_bf16(a,b,c,0,0,0)

// ------------------------------------------------ weight transpose + cast
__global__ __launch_bounds__(256)
void wt_cast(const float* __restrict__ W, bf16_t* __restrict__ Wt, int K, int N)
{
  __shared__ alignas(16) float ts[32][33];
  int t = threadIdx.x;
  int r = t>>3, c4 = (t&7)*4;
  int k0 = blockIdx.x*32, n0 = blockIdx.y*32;
  float4 v = *(const float4*)(W + (size_t)(k0+r)*N + n0 + c4);
  ts[r][c4+0]=v.x; ts[r][c4+1]=v.y; ts[r][c4+2]=v.z; ts[r][c4+3]=v.w;
  __syncthreads();
  ushort4 o;
  o.x = f2b(ts[c4+0][r]); o.y = f2b(ts[c4+1][r]);
  o.z = f2b(ts[c4+2][r]); o.w = f2b(ts[c4+3][r]);
  *(ushort4*)(Wt + (size_t)(n0+r)*K + k0 + c4) = o;
}

__global__ __launch_bounds__(256)
void concat_bias(const float* __restrict__ bq, const float* __restrict__ bk,
                 const float* __restrict__ bv, float* __restrict__ dst)
{
  int t = blockIdx.x*256 + threadIdx.x;
  if (t < 512) dst[t] = bq[t];
  else if (t < 1024) dst[t] = bk[t-512];
  else dst[t] = bv[t-1024];
}

__global__ void mx_init(unsigned* m){ if (threadIdx.x < 32) m[threadIdx.x] = 0u; }

__global__ void zero_out(float* o, long n){
  long i = (long)blockIdx.x*256 + threadIdx.x;
  if (i < n) o[i] = 0.f;
}

// pmb[m][64] bf16 = pm * dn, zero-padded rows 266..287
__global__ __launch_bounds__(256)
void pm_cast(const float* __restrict__ pm, bf16_t* __restrict__ pmb)
{
  int idx = blockIdx.x*256 + threadIdx.x;      // grid 72 -> 18432
  int r = idx>>6, c = idx&63;
  pmb[idx] = (r < 266) ? f2b(pm[r*64+c]*DN_SCALE) : (bf16_t)0;
}

// v transpose: qkv v-part -> vT[bh*64+d][4096]. grid (128, 64), block 256
__global__ __launch_bounds__(256)
void vt_trans(const bf16_t* __restrict__ qkv, bf16_t* __restrict__ vT)
{
  __shared__ ushort ts[32][36];
  int by = blockIdx.y;
  int bh = by>>1, dt = by&1, b = bh>>3, h = bh&7;
  int n0 = blockIdx.x*32;
  int t = threadIdx.x, r = t>>3, c4 = (t&7)*4;
  ushort4 v = *(const ushort4*)(qkv + ((size_t)b*4096 + n0 + r)*1536 + 1024 + h*64 + dt*32 + c4);
  ts[r][c4+0]=v.x; ts[r][c4+1]=v.y; ts[r][c4+2]=v.z; ts[r][c4+3]=v.w;
  __syncthreads();
  ushort4 o;
  o.x = ts[c4+0][r]; o.y = ts[c4+1][r]; o.z = ts[c4+2][r]; o.w = ts[c4+3][r];
  *(ushort4*)(vT + ((size_t)bh*64 + dt*32 + r)*4096 + n0 + c4) = o;
}

// ---------------------------------------------------------------- LayerNorm
__global__ __launch_bounds__(256)
void ln_kernel(const float* __restrict__ x, const float* __restrict__ g,
               const float* __restrict__ b, bf16_t* __restrict__ out)
{
  long row = blockIdx.x; int t = threadIdx.x;
  float4 v = ((const float4*)x)[row*256 + t];
  float s = v.x+v.y+v.z+v.w;
  #pragma unroll
  for (int o=32;o>0;o>>=1) s += __shfl_xor(s, o);
  __shared__ float r1[4], r2[4];
  if ((t&63)==0) r1[t>>6] = s;
  __syncthreads();
  float mu = (r1[0]+r1[1]+r1[2]+r1[3]) * (1.f/1024.f);
  float dx = v.x-mu, dy = v.y-mu, dz = v.z-mu, dw = v.w-mu;
  float ss = dx*dx+dy*dy+dz*dz+dw*dw;
  #pragma unroll
  for (int o=32;o>0;o>>=1) ss += __shfl_xor(ss, o);
  if ((t&63)==0) r2[t>>6] = ss;
  __syncthreads();
  float var = (r2[0]+r2[1]+r2[2]+r2[3]) * (1.f/1024.f);
  float rs = rsqrtf(var + 1e-5f);
  float4 gg = ((const float4*)g)[t], bb = ((const float4*)b)[t];
  ushort4 o4;
  o4.x = f2b(dx*rs*gg.x+bb.x); o4.y = f2b(dy*rs*gg.y+bb.y);
  o4.z = f2b(dz*rs*gg.z+bb.z); o4.w = f2b(dw*rs*gg.w+bb.w);
  ((ushort4*)out)[row*256+t] = o4;
}

// f32 -> bf16 cast, grid = rows (of 1024)
__global__ __launch_bounds__(256)
void cast_f32_bf16(const float* __restrict__ in, bf16_t* __restrict__ out)
{
  long i = (long)blockIdx.x*256 + threadIdx.x;
  float4 v = ((const float4*)in)[i];
  ushort4 o;
  o.x = f2b(v.x); o.y = f2b(v.y); o.z = f2b(v.z); o.w = f2b(v.w);
  ((ushort4*)out)[i] = o;
}

// ---------------------------------------------------------------- GEMM (bf16 MFMA)
// 128x128 tile, BK=32, 4 waves, double-buffered LDS (2-phase: stage tile t+1
// BEFORE computing tile t; one __syncthreads per step).  PROVEN OPTIMUM here:
// manual vmcnt/raw-barrier variants all measured slower (R6/R8/R10); larger
// staging chunks (32MB) break L2 residency (R12).  XCD-bijective chunking +
// 16-row supertile block remap for L2 locality (requires nwg%8==0, Mtiles%16==0).
template<int RES, int GELU, int GATEF, int OBF>
__global__ __launch_bounds__(256)
void gemm_bt(const bf16_t* __restrict__ A, int lda,
             const bf16_t* __restrict__ Bt, int ldb,
             const float* __restrict__ bias,
             const float* res,
             const float* gatef,
             void* Cout, int N, int K)
{
  __shared__ alignas(16) bf16_t As[2][128*32];
  __shared__ alignas(16) bf16_t Bs[2][128*32];
  const int tid = threadIdx.x;
  const int wid = tid>>6, lane = tid&63;
  const int l15 = lane&15, l4 = lane>>4;
  const int wm = wid>>1, wn = wid&1;

  // ---- block remap: XCD-contiguous chunks over a ty-fast supertiled order
  const int NX = gridDim.x;
  const int nwg = NX * gridDim.y;
  const int lid = blockIdx.y*NX + blockIdx.x;
  const int qc = nwg>>3;
  const int wgid = (lid&7)*qc + (lid>>3);          // nwg%8==0 bijective chunk
  const int stripe = wgid / (16*NX);
  const int rem    = wgid % (16*NX);
  const long m0 = (long)(stripe*16 + (rem & 15))*128;
  const long n0 = (long)(rem >> 4)*128;

  f32x4 acc[4][4];
  #pragma unroll
  for (int i=0;i<4;i++)
    #pragma unroll
    for (int j=0;j<4;j++) acc[i][j] = f32x4{0.f,0.f,0.f,0.f};

  const bf16_t* ga = A  + (size_t)(m0 + (tid>>2))*lda + (tid&3)*8;
  const bf16_t* gb = Bt + (size_t)(n0 + (tid>>2))*ldb + (tid&3)*8;

  auto STAGE = [&](int buf){
    GLOAD_LDS16(ga,                   &As[buf][wid*512]);
    GLOAD_LDS16(ga + (size_t)64*lda,  &As[buf][2048 + wid*512]);
    GLOAD_LDS16(gb,                   &Bs[buf][wid*512]);
    GLOAD_LDS16(gb + (size_t)64*ldb,  &Bs[buf][2048 + wid*512]);
    ga += 32; gb += 32;
  };

  const int nt = K >> 5;
  STAGE(0);
  __syncthreads();                      // drains vmcnt(0): tile 0 resident
  int cur = 0;
  for (int t = 0; t < nt; ++t){
    if (t+1 < nt) STAGE(cur^1);         // issue next-tile loads FIRST
    bf16x8 af[4], bfr[4];
    #pragma unroll
    for (int i=0;i<4;i++){
      af[i]  = *(const bf16x8*)(&As[cur][(wm*64 + i*16 + l15)*32 + l4*8]);
      bfr[i] = *(const bf16x8*)(&Bs[cur][(wn*64 + i*16 + l15)*32 + l4*8]);
    }
    #pragma unroll
    for (int i=0;i<4;i++)
      #pragma unroll
      for (int j=0;j<4;j++)
        acc[i][j] = MFMA16(af[i], bfr[j], acc[i][j]);
    __syncthreads();                    // drains vmcnt(0): next tile resident,
    cur ^= 1;                           // and all reads of As[cur] complete
  }

  #pragma unroll
  for (int i=0;i<4;i++){
    #pragma unroll
    for (int j=0;j<4;j++){
      #pragma unroll
      for (int r=0;r<4;r++){
        long row = m0 + wm*64 + i*16 + l4*4 + r;
        long col = n0 + wn*64 + j*16 + l15;
        float v = acc[i][j][r] + bias[col];
        if constexpr (RES)   v += res[row*(long)N + col];
        if constexpr (GELU)  v = 0.5f*v*(1.0f + erf_fast(v*0.70710678118654752f));
        if constexpr (GATEF) v *= gatef[row*(long)N + col];
        if constexpr (OBF)  ((bf16_t*)Cout)[row*(long)N + col] = f2b(v);
        else                ((float* )Cout)[row*(long)N + col] = v;
      }
    }
  }
}

// ---------------------------------------------------------------- FAVOR (MFMA)
// qkv: [16384][1536] bf16, q @ h*64, k @ 512+h*64, v @ 1024+h*64.

// dd-max over all (n,m) per bh. grid (64, 32), block 256 (4 waves x 16 rows)
__global__ __launch_bounds__(256,2)
void favor_kmax2(const bf16_t* __restrict__ qkv, const bf16_t* __restrict__ pmb,
                 unsigned* __restrict__ mxk)
{
  int bh = blockIdx.y, b = bh>>3, h = bh&7;
  int t = threadIdx.x, wid = t>>6, lane = t&63;
  int l15 = lane&15, l4 = lane>>4;
  int n0 = blockIdx.x*64, row0 = wid*16;
  f32x4 acc[18];
  #pragma unroll
  for (int c=0;c<18;c++) acc[c] = f32x4{0.f,0.f,0.f,0.f};
  const bf16_t* abase = qkv + ((size_t)(b*4096) + n0 + row0 + l15)*1536 + 512 + h*64;
  #pragma unroll
  for (int kh=0;kh<2;kh++){
    bf16x8 a = *(const bf16x8*)(abase + kh*32 + l4*8);
    #pragma unroll
    for (int ct=0;ct<18;ct++){
      bf16x8 bb = *(const bf16x8*)(pmb + (ct*16+l15)*64 + kh*32 + l4*8);
      acc[ct] = MFMA16(a, bb, acc[ct]);
    }
  }
  float mx = -3e38f;
  #pragma unroll
  for (int ct=0;ct<18;ct++){
    if (ct*16 + l15 < 266){
      #pragma unroll
      for (int r=0;r<4;r++) mx = fmaxf(mx, acc[ct][r]);
    }
  }
  #pragma unroll
  for (int o=32;o>0;o>>=1) mx = fmaxf(mx, __shfl_xor(mx, o));
  __shared__ float red[4];
  if (lane==0) red[wid] = mx;
  __syncthreads();
  if (t==0){
    float m2 = fmaxf(fmaxf(red[0],red[1]),fmaxf(red[2],red[3]));
    atomicMax(mxk + bh, encf(m2));
  }
}

// kp = ratio*(exp(dd - diag - MX)+eps) written DIRECTLY transposed to
// kpT[bhl][MPAD m][4096 n]; diag computed in-kernel from the same fragments.
// grid (64, KG), block 256
__global__ __launch_bounds__(256,2)
void favor_kp(const bf16_t* __restrict__ qkv, const bf16_t* __restrict__ pmb,
              const unsigned* __restrict__ mxk, bf16_t* __restrict__ kpT, int bh0)
{
  int bhl = blockIdx.y, bh = bh0 + bhl, b = bh>>3, h = bh&7;
  int t = threadIdx.x, wid = t>>6, lane = t&63;
  int l15 = lane&15, l4 = lane>>4;
  int n0 = blockIdx.x*64, row0 = wid*16;
  f32x4 acc[18];
  #pragma unroll
  for (int c=0;c<18;c++) acc[c] = f32x4{0.f,0.f,0.f,0.f};
  const bf16_t* abase = qkv + ((size_t)(b*4096) + n0 + row0 + l15)*1536 + 512 + h*64;
  float rsq = 0.f;
  #pragma unroll
  for (int kh=0;kh<2;kh++){
    bf16x8 a = *(const bf16x8*)(abase + kh*32 + l4*8);
    #pragma unroll
    for (int e=0;e<8;e++){ float v = b2f((bf16_t)a[e]); rsq += v*v; }
    #pragma unroll
    for (int ct=0;ct<18;ct++){
      bf16x8 bb = *(const bf16x8*)(pmb + (ct*16+l15)*64 + kh*32 + l4*8);
      acc[ct] = MFMA16(a, bb, acc[ct]);
    }
  }
  rsq += __shfl_xor(rsq, 16);
  rsq += __shfl_xor(rsq, 32);                 // lanes sharing l15: full row sumsq
  float MX = decf(mxk[bh]);
  constexpr float DSC = 0.5f*DN_SCALE*DN_SCALE;
  float dg[4];
  #pragma unroll
  for (int r=0;r<4;r++) dg[r] = DSC * __shfl(rsq, l4*4 + r);
  #pragma unroll
  for (int ct=0;ct<18;ct++){
    int col = ct*16 + l15;
    ushort4 o;
    if (col < 266){
      o.x = f2b(RATIO*(__expf(acc[ct][0] - dg[0] - MX) + KEPS));
      o.y = f2b(RATIO*(__expf(acc[ct][1] - dg[1] - MX) + KEPS));
      o.z = f2b(RATIO*(__expf(acc[ct][2] - dg[2] - MX) + KEPS));
      o.w = f2b(RATIO*(__expf(acc[ct][3] - dg[3] - MX) + KEPS));
    } else { o.x=0; o.y=0; o.z=0; o.w=0; }
    *(ushort4*)(kpT + ((size_t)bhl*MPAD + col)*4096 + n0 + row0 + l4*4) = o;
  }
}

// ctx partial GEMM (K-split x4) with fused partial ksum. grid (17, 4, KG).
__global__ __launch_bounds__(256,2)
void ctx_gemm(const bf16_t* __restrict__ kpT, const bf16_t* __restrict__ vT,
              float* __restrict__ ctxP, float* __restrict__ ksumP, int bh0)
{
  int m0 = blockIdx.x*16, ks = blockIdx.y, bhl = blockIdx.z, bh = bh0 + bhl;
  int t = threadIdx.x, wid = t>>6, lane = t&63;
  int l15 = lane&15, l4 = lane>>4;
  f32x4 acc[4];
  #pragma unroll
  for (int c=0;c<4;c++) acc[c] = f32x4{0.f,0.f,0.f,0.f};
  const bf16_t* Abase = kpT + ((size_t)bhl*MPAD + m0 + l15)*4096;
  const bf16_t* Bbase = vT + ((size_t)bh*64)*4096;
  const int kb = ks*1024 + wid*256;
  float ksp = 0.f;
  for (int k = kb; k < kb + 256; k += 32){
    bf16x8 a = *(const bf16x8*)(Abase + k + l4*8);
    #pragma unroll
    for (int e=0;e<8;e++) ksp += b2f((bf16_t)a[e]);
    #pragma unroll
    for (int ct=0;ct<4;ct++){
      bf16x8 bb = *(const bf16x8*)(Bbase + (size_t)(ct*16+l15)*4096 + k + l4*8);
      acc[ct] = MFMA16(a, bb, acc[ct]);
    }
  }
  // row-sum partials: combine the 4 lanes sharing l15
  ksp += __shfl_xor(ksp, 16);
  ksp += __shfl_xor(ksp, 32);
  __shared__ float red[4][4][16][16];
  __shared__ float ksred[4][16];
  if (l4 == 0) ksred[wid][l15] = ksp;
  #pragma unroll
  for (int ct=0;ct<4;ct++)
    #pragma unroll
    for (int r=0;r<4;r++) red[wid][ct][l4*4+r][l15] = acc[ct][r];
  __syncthreads();
  #pragma unroll
  for (int i=0;i<4;i++){
    int e = i*256 + t;
    int ct = e>>8, row = (e>>4)&15, col = e&15;
    float s = ((red[0][ct][row][col] + red[1][ct][row][col])
             + (red[2][ct][row][col] + red[3][ct][row][col]));
    ctxP[(((size_t)bhl*4 + ks)*272 + m0 + row)*64 + ct*16 + col] = s;
  }
  if (t < 16){
    float s2 = ksred[0][t] + ksred[1][t] + ksred[2][t] + ksred[3][t];
    ksumP[((size_t)bhl*4 + ks)*272 + m0 + t] = s2;
  }
}

// reduce K-split partials -> ctxT[bh][d][MPAD m] bf16 (zero pad m>=272) and
// ksumf[bh][m].  grid (72, KG)
__global__ __launch_bounds__(256)
void ctx_reduce(const float* __restrict__ ctxP, const float* __restrict__ ksumP,
                bf16_t* __restrict__ ctxT, float* __restrict__ ksumf, int bh0)
{
  int bhl = blockIdx.y, bh = bh0 + bhl;
  int idx = blockIdx.x*256 + threadIdx.x;   // < 18432 = 288*64
  int m = idx>>6, d = idx&63;
  float s = 0.f;
  if (m < 272){
    #pragma unroll
    for (int ks=0;ks<4;ks++)
      s += ctxP[(((size_t)bhl*4 + ks)*272 + m)*64 + d];
  }
  ctxT[((size_t)bh*64 + d)*MPAD + m] = f2b(s);
  if (idx < 272){
    float s2 = 0.f;
    #pragma unroll
    for (int ks=0;ks<4;ks++)
      s2 += ksumP[(((size_t)bhl*4 + ks)*272) + idx];
    ksumf[(size_t)bh*MPAD + idx] = s2;
  }
}

// fused q-side: dd MFMA -> in-kernel diag -> rowmax -> qp -> LDS ->
// out MFMA * dinv -> attn. grid (64, 32), block 256
__global__ __launch_bounds__(256,2)
void favor_q(const bf16_t* __restrict__ qkv, const bf16_t* __restrict__ pmb,
             const float* __restrict__ ksumf,
             const bf16_t* __restrict__ ctxT, bf16_t* __restrict__ attn)
{
  __shared__ alignas(16) ushort qpLds[64*296];
  __shared__ float ksLds[288];
  int bh = blockIdx.y, b = bh>>3, h = bh&7;
  int t = threadIdx.x, wid = t>>6, lane = t&63;
  int l15 = lane&15, l4 = lane>>4;
  int n0 = blockIdx.x*64, row0 = wid*16;
  ksLds[t] = (t < 272) ? ksumf[(size_t)bh*MPAD + t] : 0.f;
  if (t < 32) ksLds[256+t] = (256+t < 272) ? ksumf[(size_t)bh*MPAD + 256 + t] : 0.f;
  __syncthreads();

  f32x4 acc[18];
  #pragma unroll
  for (int c=0;c<18;c++) acc[c] = f32x4{0.f,0.f,0.f,0.f};
  const bf16_t* abase = qkv + ((size_t)(b*4096) + n0 + row0 + l15)*1536 + h*64;
  float rsq = 0.f;
  #pragma unroll
  for (int kh=0;kh<2;kh++){
    bf16x8 a = *(const bf16x8*)(abase + kh*32 + l4*8);
    #pragma unroll
    for (int e=0;e<8;e++){ float v = b2f((bf16_t)a[e]); rsq += v*v; }
    #pragma unroll
    for (int ct=0;ct<18;ct++){
      bf16x8 bb = *(const bf16x8*)(pmb + (ct*16+l15)*64 + kh*32 + l4*8);
      acc[ct] = MFMA16(a, bb, acc[ct]);
    }
  }
  rsq += __shfl_xor(rsq, 16);
  rsq += __shfl_xor(rsq, 32);
  constexpr float DSC = 0.5f*DN_SCALE*DN_SCALE;
  float dg[4];
  #pragma unroll
  for (int r=0;r<4;r++) dg[r] = DSC * __shfl(rsq, l4*4 + r);

  // per-row max over valid cols
  float mxr[4] = {-3e38f,-3e38f,-3e38f,-3e38f};
  #pragma unroll
  for (int ct=0;ct<18;ct++){
    if (ct*16 + l15 < 266){
      #pragma unroll
      for (int r=0;r<4;r++) mxr[r] = fmaxf(mxr[r], acc[ct][r]);
    }
  }
  #pragma unroll
  for (int r=0;r<4;r++){
    mxr[r] = fmaxf(mxr[r], __shfl_xor(mxr[r], 1));
    mxr[r] = fmaxf(mxr[r], __shfl_xor(mxr[r], 2));
    mxr[r] = fmaxf(mxr[r], __shfl_xor(mxr[r], 4));
    mxr[r] = fmaxf(mxr[r], __shfl_xor(mxr[r], 8));
  }
  float den[4] = {0.f,0.f,0.f,0.f};
  #pragma unroll
  for (int ct=0;ct<18;ct++){
    int col = ct*16 + l15;
    float ks = ksLds[col];
    #pragma unroll
    for (int r=0;r<4;r++){
      float qpv = 0.f;
      if (col < 266){
        qpv = RATIO*(__expf(acc[ct][r] - dg[r] - mxr[r]) + KEPS);
        den[r] += qpv*ks;
      }
      qpLds[(row0 + l4*4 + r)*296 + col] = f2b(qpv);
    }
  }
  float dinv[4];
  #pragma unroll
  for (int r=0;r<4;r++){
    den[r] += __shfl_xor(den[r], 1);
    den[r] += __shfl_xor(den[r], 2);
    den[r] += __shfl_xor(den[r], 4);
    den[r] += __shfl_xor(den[r], 8);
    dinv[r] = 1.0f/den[r];
  }
  __syncthreads();

  f32x4 o2[4];
  #pragma unroll
  for (int c=0;c<4;c++) o2[c] = f32x4{0.f,0.f,0.f,0.f};
  const bf16_t* Bbase = ctxT + (size_t)bh*64*MPAD;
  #pragma unroll
  for (int kk=0;kk<9;kk++){
    int k0 = kk*32;
    bf16x8 a = *(const bf16x8*)&qpLds[(row0 + l15)*296 + k0 + l4*8];
    #pragma unroll
    for (int ct=0;ct<4;ct++){
      bf16x8 bb = *(const bf16x8*)(Bbase + (size_t)(ct*16+l15)*MPAD + k0 + l4*8);
      o2[ct] = MFMA16(a, bb, o2[ct]);
    }
  }
  #pragma unroll
  for (int ct=0;ct<4;ct++)
    #pragma unroll
    for (int r=0;r<4;r++)
      attn[((size_t)(b*4096) + n0 + row0 + l4*4 + r)*512 + h*64 + ct*16 + l15]
        = f2b(o2[ct][r] * dinv[r]);
}

// ---------------------------------------------------------------- launcher
extern "C" void kernel_launch(void* const* d_in, const int* in_sizes, int n_in,
                              void* d_out, int out_size, void* d_ws, size_t ws_size,
                              hipStream_t stream)
{
  (void)in_sizes; (void)n_in; (void)out_size;
  const float* x      = (const float*)d_in[0];
  const float* proj_w = (const float*)d_in[1];
  const float* proj_b = (const float*)d_in[2];
  const float* ln1_g  = (const float*)d_in[3];
  const float* ln1_b  = (const float*)d_in[4];
  const float* wq     = (const float*)d_in[5];
  const float* bq     = (const float*)d_in[6];
  const float* wk     = (const float*)d_in[7];
  const float* bk     = (const float*)d_in[8];
  const float* wv     = (const float*)d_in[9];
  const float* bv     = (const float*)d_in[10];
  const float* wo     = (const float*)d_in[11];
  const float* bo     = (const float*)d_in[12];
  const float* pm     = (const float*)d_in[13];
  const float* ln2_g  = (const float*)d_in[14];
  const float* ln2_b  = (const float*)d_in[15];
  const float* w1     = (const float*)d_in[16];
  const float* b1     = (const float*)d_in[17];
  const float* w2     = (const float*)d_in[18];
  const float* b2     = (const float*)d_in[19];
  float* out = (float*)d_out;
  const size_t MB = 1ull<<20;

  char* ws = (char*)d_ws;
  size_t off = 0;
  auto alloc = [&](size_t bytes)->void*{ void* p = ws + off; off += (bytes + 255) & ~(size_t)255; return p; };
  bf16_t* Wt_proj = (bf16_t*)alloc(2ul*1024*1024);
  bf16_t* Wt_qkv  = (bf16_t*)alloc(2ul*1536*1024);
  bf16_t* Wt_o    = (bf16_t*)alloc(2ul*1024*512);
  bf16_t* Wt_1    = (bf16_t*)alloc(2ul*4096*1024);
  bf16_t* Wt_2    = (bf16_t*)alloc(2ul*1024*4096);
  float*  bqkv    = (float*) alloc(4ul*1536);
  unsigned* mxk   = (unsigned*)alloc(4ul*32);
  bf16_t* pmb     = (bf16_t*)alloc(2ul*MPAD*64);
  float*  ksumf   = (float*) alloc(4ul*32*MPAD);
  bf16_t* ctxT    = (bf16_t*)alloc(2ul*32*64*MPAD);
  float*  ctxP    = (float*) alloc(4ul*32*4*272*64);  // K-split partials (KG<=32)
  float*  ksumP   = (float*) alloc(4ul*32*4*272);
  char*   R       = (char*)  alloc(0);
  size_t R_avail = (ws_size > off) ? ws_size - off : 0;

  // tiers: chunk sizes fixed at the L2-friendly proven values (ACH=8192, NC=2);
  // only the k-side pass count scales with workspace.
  int KG, NC = 2; long ACH = 8192;
  if      (R_avail >= 124*MB){ KG = 32; }          // single k-side pass
  else if (R_avail >=  84*MB){ KG = 8;  }
  else if (R_avail >=  67*MB){ KG = 4;  NC = 4; }
  else { zero_out<<<dim3(65536), 256, 0, stream>>>(out, 16777216L); return; }

  // R overlays (stream-serialized disjoint lifetimes)
  bf16_t* qkv  = (bf16_t*)(R);               // 48MB   [LN1/qkv .. favor_q]
  bf16_t* h1c  = (bf16_t*)(R + 48*MB);       // 16MB   [phase A]
  bf16_t* kpT  = (bf16_t*)(R + 48*MB);       // KG*2.36MB [k-side]
  bf16_t* attn = (bf16_t*)(R + 48*MB);       // 16MB   [favor_q .. wo]
  long    CH   = 16384/NC;
  bf16_t* h2c  = (bf16_t*)(R);               // CH*2KB [phase 5]
  bf16_t* ff1c = (bf16_t*)(R + 16*MB);       // CH*8KB
  bf16_t* vT   = (bf16_t*)d_out;             // 16.8MB scratch in d_out (dead till wo)

  // 1) weights -> bf16 transposed, pm cast
  wt_cast<<<dim3(32,32), 256, 0, stream>>>(proj_w, Wt_proj, 1024, 1024);
  wt_cast<<<dim3(32,16), 256, 0, stream>>>(wq, Wt_qkv,              1024, 512);
  wt_cast<<<dim3(32,16), 256, 0, stream>>>(wk, Wt_qkv + 512*1024,   1024, 512);
  wt_cast<<<dim3(32,16), 256, 0, stream>>>(wv, Wt_qkv + 1024*1024,  1024, 512);
  wt_cast<<<dim3(16,32), 256, 0, stream>>>(wo, Wt_o, 512, 1024);
  wt_cast<<<dim3(32,128),256, 0, stream>>>(w1, Wt_1, 1024, 4096);
  wt_cast<<<dim3(128,32),256, 0, stream>>>(w2, Wt_2, 4096, 1024);
  concat_bias<<<dim3(6), 256, 0, stream>>>(bq, bk, bv, bqkv);
  pm_cast<<<dim3(72), 256, 0, stream>>>(pm, pmb);

  // 2) phase A: LN1 + qkv GEMM, 2 chunks of 8192 rows (L2-resident staging)
  for (long c = 0; c < 16384/ACH; c++){
    ln_kernel<<<dim3((unsigned)ACH), 256, 0, stream>>>(x + (size_t)c*ACH*1024, ln1_g, ln1_b, h1c);
    gemm_bt<0,0,0,1><<<dim3(12,(unsigned)(ACH/128)), 256, 0, stream>>>(h1c, 1024, Wt_qkv, 1024,
        bqkv, nullptr, nullptr, qkv + (size_t)c*ACH*1536, 1536, 1024);
  }

  // 3) FAVOR
  vt_trans<<<dim3(128,64), 256, 0, stream>>>(qkv, vT);
  mx_init<<<dim3(1), 64, 0, stream>>>(mxk);
  favor_kmax2<<<dim3(64,32), 256, 0, stream>>>(qkv, pmb, mxk);
  for (int g = 0; g < 32; g += KG){
    favor_kp<<<dim3(64,KG), 256, 0, stream>>>(qkv, pmb, mxk, kpT, g);
    ctx_gemm<<<dim3(17,4,KG), 256, 0, stream>>>(kpT, vT, ctxP, ksumP, g);
    ctx_reduce<<<dim3(72,KG), 256, 0, stream>>>(ctxP, ksumP, ctxT, ksumf, g);
  }
  favor_q<<<dim3(64,32), 256, 0, stream>>>(qkv, pmb, ksumf, ctxT, attn);

  // 4) x2 = x + attn @ wo + bo -> d_out (f32); overwrites vT scratch
  gemm_bt<1,0,0,0><<<dim3(8,128), 256, 0, stream>>>(attn, 512, Wt_o, 512,
      bo, x, nullptr, out, 1024, 512);

  // 5) per chunk: LN2 -> ff1(gelu) -> ff2(+res, in-place) -> gate(in-place)
  for (int c = 0; c < NC; c++){
    float* xrow = out + (size_t)c*CH*1024;
    ln_kernel<<<dim3((unsigned)CH), 256, 0, stream>>>(xrow, ln2_g, ln2_b, h2c);
    gemm_bt<0,1,0,1><<<dim3(32,(unsigned)(CH/128)), 256, 0, stream>>>(h2c, 1024, Wt_1, 1024,
        b1, nullptr, nullptr, ff1c, 4096, 1024);
    gemm_bt<1,0,0,0><<<dim3(8,(unsigned)(CH/128)), 256, 0, stream>>>(ff1c, 4096, Wt_2, 4096,
        b2, xrow, nullptr, xrow, 1024, 4096);
    cast_f32_bf16<<<dim3((unsigned)CH), 256, 0, stream>>>(x + (size_t)c*CH*1024, h2c);
    gemm_bt<0,0,1,0><<<dim3(8,(unsigned)(CH/128)), 256, 0, stream>>>(h2c, 1024, Wt_proj, 1024,
        proj_b, nullptr, xrow, xrow, 1024, 1024);
  }
}

// Round 14
// 932.593 us; speedup vs baseline: 1.0889x; 1.0144x over previous
//
#include <hip/hip_runtime.h>
#include <math.h>

typedef unsigned short bf16_t;
using bf16x8 = __attribute__((ext_vector_type(8))) short;
using f32x4  = __attribute__((ext_vector_type(4))) float;

#define DEVFN static __device__ __forceinline__

DEVFN float b2f(bf16_t u){ unsigned v=((unsigned)u)<<16; float f; __builtin_memcpy(&f,&v,4); return f; }
DEVFN bf16_t f2b(float f){ unsigned u; __builtin_memcpy(&u,&f,4); u += 0x7fffu + ((u>>16)&1u); return (bf16_t)(u>>16); }
DEVFN unsigned encf(float f){ unsigned u=__float_as_uint(f); return (u&0x80000000u)? ~u : (u|0x80000000u); }
DEVFN float decf(unsigned e){ return __uint_as_float((e&0x80000000u)? (e^0x80000000u) : ~e); }

// erf via Abramowitz-Stegun 7.1.26, |abs err| <= 1.5e-7
DEVFN float erf_fast(float x){
  float ax = fabsf(x);
  float t = __builtin_amdgcn_rcpf(1.0f + 0.3275911f*ax);
  float y = t*(0.254829592f + t*(-0.284496736f + t*(1.421413741f
          + t*(-1.453152027f + t*1.061405429f))));
  float r = 1.0f - y*__expf(-ax*ax);
  return copysignf(r, x);
}

constexpr float DN_SCALE = 0.35355339059327373f;   // 64^-0.25
constexpr float RATIO    = 0.06131393394849658f;   // 266^-0.5
constexpr float KEPS     = 1e-4f;
#define MPAD 288   // 266 features padded to 9*32

#define GLOAD_LDS16(g, l) __builtin_amdgcn_global_load_lds( \
    (__attribute__((address_space(1))) void*)(g), \
    (__attribute__((address_space(3))) void*)(l), 16, 0, 0)

#define MFMA16(a,b,c) __builtin_amdgcn_mfma_f32_16x16x32_bf16(a,b,c,0,0,0)

// ------------------------------------------------ weight transpose + cast
__global__ __launch_bounds__(256)
void wt_cast(const float* __restrict__ W, bf16_t* __restrict__ Wt, int K, int N)
{
  __shared__ alignas(16) float ts[32][33];
  int t = threadIdx.x;
  int r = t>>3, c4 = (t&7)*4;
  int k0 = blockIdx.x*32, n0 = blockIdx.y*32;
  float4 v = *(const float4*)(W + (size_t)(k0+r)*N + n0 + c4);
  ts[r][c4+0]=v.x; ts[r][c4+1]=v.y; ts[r][c4+2]=v.z; ts[r][c4+3]=v.w;
  __syncthreads();
  ushort4 o;
  o.x = f2b(ts[c4+0][r]); o.y = f2b(ts[c4+1][r]);
  o.z = f2b(ts[c4+2][r]); o.w = f2b(ts[c4+3][r]);
  *(ushort4*)(Wt + (size_t)(n0+r)*K + k0 + c4) = o;
}

__global__ __launch_bounds__(256)
void concat_bias(const float* __restrict__ bq, const float* __restrict__ bk,
                 const float* __restrict__ bv, float* __restrict__ dst)
{
  int t = blockIdx.x*256 + threadIdx.x;
  if (t < 512) dst[t] = bq[t];
  else if (t < 1024) dst[t] = bk[t-512];
  else dst[t] = bv[t-1024];
}

__global__ void mx_init(unsigned* m){ if (threadIdx.x < 32) m[threadIdx.x] = 0u; }

__global__ void zero_out(float* o, long n){
  long i = (long)blockIdx.x*256 + threadIdx.x;
  if (i < n) o[i] = 0.f;
}

// pmb[m][64] bf16 = pm * dn, zero-padded rows 266..287
__global__ __launch_bounds__(256)
void pm_cast(const float* __restrict__ pm, bf16_t* __restrict__ pmb)
{
  int idx = blockIdx.x*256 + threadIdx.x;      // grid 72 -> 18432
  int r = idx>>6, c = idx&63;
  pmb[idx] = (r < 266) ? f2b(pm[r*64+c]*DN_SCALE) : (bf16_t)0;
}

// v transpose: qkv v-part -> vT[bh*64+d][4096]. grid (128, 64), block 256
__global__ __launch_bounds__(256)
void vt_trans(const bf16_t* __restrict__ qkv, bf16_t* __restrict__ vT)
{
  __shared__ ushort ts[32][36];
  int by = blockIdx.y;
  int bh = by>>1, dt = by&1, b = bh>>3, h = bh&7;
  int n0 = blockIdx.x*32;
  int t = threadIdx.x, r = t>>3, c4 = (t&7)*4;
  ushort4 v = *(const ushort4*)(qkv + ((size_t)b*4096 + n0 + r)*1536 + 1024 + h*64 + dt*32 + c4);
  ts[r][c4+0]=v.x; ts[r][c4+1]=v.y; ts[r][c4+2]=v.z; ts[r][c4+3]=v.w;
  __syncthreads();
  ushort4 o;
  o.x = ts[c4+0][r]; o.y = ts[c4+1][r]; o.z = ts[c4+2][r]; o.w = ts[c4+3][r];
  *(ushort4*)(vT + ((size_t)bh*64 + dt*32 + r)*4096 + n0 + c4) = o;
}

// ---------------------------------------------------------------- LayerNorm
__global__ __launch_bounds__(256)
void ln_kernel(const float* __restrict__ x, const float* __restrict__ g,
               const float* __restrict__ b, bf16_t* __restrict__ out)
{
  long row = blockIdx.x; int t = threadIdx.x;
  float4 v = ((const float4*)x)[row*256 + t];
  float s = v.x+v.y+v.z+v.w;
  #pragma unroll
  for (int o=32;o>0;o>>=1) s += __shfl_xor(s, o);
  __shared__ float r1[4], r2[4];
  if ((t&63)==0) r1[t>>6] = s;
  __syncthreads();
  float mu = (r1[0]+r1[1]+r1[2]+r1[3]) * (1.f/1024.f);
  float dx = v.x-mu, dy = v.y-mu, dz = v.z-mu, dw = v.w-mu;
  float ss = dx*dx+dy*dy+dz*dz+dw*dw;
  #pragma unroll
  for (int o=32;o>0;o>>=1) ss += __shfl_xor(ss, o);
  if ((t&63)==0) r2[t>>6] = ss;
  __syncthreads();
  float var = (r2[0]+r2[1]+r2[2]+r2[3]) * (1.f/1024.f);
  float rs = rsqrtf(var + 1e-5f);
  float4 gg = ((const float4*)g)[t], bb = ((const float4*)b)[t];
  ushort4 o4;
  o4.x = f2b(dx*rs*gg.x+bb.x); o4.y = f2b(dy*rs*gg.y+bb.y);
  o4.z = f2b(dz*rs*gg.z+bb.z); o4.w = f2b(dw*rs*gg.w+bb.w);
  ((ushort4*)out)[row*256+t] = o4;
}

// f32 -> bf16 cast, grid = rows (of 1024)
__global__ __launch_bounds__(256)
void cast_f32_bf16(const float* __restrict__ in, bf16_t* __restrict__ out)
{
  long i = (long)blockIdx.x*256 + threadIdx.x;
  float4 v = ((const float4*)in)[i];
  ushort4 o;
  o.x = f2b(v.x); o.y = f2b(v.y); o.z = f2b(v.z); o.w = f2b(v.w);
  ((ushort4*)out)[i] = o;
}

// ---------------------------------------------------------------- GEMM (bf16 MFMA)
// 128x128 tile, BK=32, 4 waves, double-buffered LDS (2-phase: stage tile t+1
// BEFORE computing tile t; one __syncthreads per step).  PROVEN OPTIMUM here:
// manual vmcnt/raw-barrier variants all measured slower (R6/R8/R10); larger
// staging chunks break L2 residency (R12).  XCD-bijective chunking +
// 16-row supertile block remap for L2 locality (requires nwg%8==0, Mtiles%16==0).
template<int RES, int GELU, int GATEF, int OBF>
__global__ __launch_bounds__(256)
void gemm_bt(const bf16_t* __restrict__ A, int lda,
             const bf16_t* __restrict__ Bt, int ldb,
             const float* __restrict__ bias,
             const float* res,
             const float* gatef,
             void* Cout, int N, int K)
{
  __shared__ alignas(16) bf16_t As[2][128*32];
  __shared__ alignas(16) bf16_t Bs[2][128*32];
  const int tid = threadIdx.x;
  const int wid = tid>>6, lane = tid&63;
  const int l15 = lane&15, l4 = lane>>4;
  const int wm = wid>>1, wn = wid&1;

  // ---- block remap: XCD-contiguous chunks over a ty-fast supertiled order
  const int NX = gridDim.x;
  const int nwg = NX * gridDim.y;
  const int lid = blockIdx.y*NX + blockIdx.x;
  const int qc = nwg>>3;
  const int wgid = (lid&7)*qc + (lid>>3);          // nwg%8==0 bijective chunk
  const int stripe = wgid / (16*NX);
  const int rem    = wgid % (16*NX);
  const long m0 = (long)(stripe*16 + (rem & 15))*128;
  const long n0 = (long)(rem >> 4)*128;

  f32x4 acc[4][4];
  #pragma unroll
  for (int i=0;i<4;i++)
    #pragma unroll
    for (int j=0;j<4;j++) acc[i][j] = f32x4{0.f,0.f,0.f,0.f};

  const bf16_t* ga = A  + (size_t)(m0 + (tid>>2))*lda + (tid&3)*8;
  const bf16_t* gb = Bt + (size_t)(n0 + (tid>>2))*ldb + (tid&3)*8;

  auto STAGE = [&](int buf){
    GLOAD_LDS16(ga,                   &As[buf][wid*512]);
    GLOAD_LDS16(ga + (size_t)64*lda,  &As[buf][2048 + wid*512]);
    GLOAD_LDS16(gb,                   &Bs[buf][wid*512]);
    GLOAD_LDS16(gb + (size_t)64*ldb,  &Bs[buf][2048 + wid*512]);
    ga += 32; gb += 32;
  };

  const int nt = K >> 5;
  STAGE(0);
  __syncthreads();                      // drains vmcnt(0): tile 0 resident
  int cur = 0;
  for (int t = 0; t < nt; ++t){
    if (t+1 < nt) STAGE(cur^1);         // issue next-tile loads FIRST
    bf16x8 af[4], bfr[4];
    #pragma unroll
    for (int i=0;i<4;i++){
      af[i]  = *(const bf16x8*)(&As[cur][(wm*64 + i*16 + l15)*32 + l4*8]);
      bfr[i] = *(const bf16x8*)(&Bs[cur][(wn*64 + i*16 + l15)*32 + l4*8]);
    }
    #pragma unroll
    for (int i=0;i<4;i++)
      #pragma unroll
      for (int j=0;j<4;j++)
        acc[i][j] = MFMA16(af[i], bfr[j], acc[i][j]);
    __syncthreads();                    // drains vmcnt(0): next tile resident,
    cur ^= 1;                           // and all reads of As[cur] complete
  }

  #pragma unroll
  for (int i=0;i<4;i++){
    #pragma unroll
    for (int j=0;j<4;j++){
      #pragma unroll
      for (int r=0;r<4;r++){
        long row = m0 + wm*64 + i*16 + l4*4 + r;
        long col = n0 + wn*64 + j*16 + l15;
        float v = acc[i][j][r] + bias[col];
        if constexpr (RES)   v += res[row*(long)N + col];
        if constexpr (GELU)  v = 0.5f*v*(1.0f + erf_fast(v*0.70710678118654752f));
        if constexpr (GATEF) v *= gatef[row*(long)N + col];
        if constexpr (OBF)  ((bf16_t*)Cout)[row*(long)N + col] = f2b(v);
        else                ((float* )Cout)[row*(long)N + col] = v;
      }
    }
  }
}

// ---------------------------------------------------------------- FAVOR (MFMA)
// qkv: [16384][1536] bf16, q @ h*64, k @ 512+h*64, v @ 1024+h*64.

// dd-max over all (n,m) per bh. grid (64, 32), block 256 (4 waves x 16 rows)
__global__ __launch_bounds__(256,2)
void favor_kmax2(const bf16_t* __restrict__ qkv, const bf16_t* __restrict__ pmb,
                 unsigned* __restrict__ mxk)
{
  int bh = blockIdx.y, b = bh>>3, h = bh&7;
  int t = threadIdx.x, wid = t>>6, lane = t&63;
  int l15 = lane&15, l4 = lane>>4;
  int n0 = blockIdx.x*64, row0 = wid*16;
  f32x4 acc[18];
  #pragma unroll
  for (int c=0;c<18;c++) acc[c] = f32x4{0.f,0.f,0.f,0.f};
  const bf16_t* abase = qkv + ((size_t)(b*4096) + n0 + row0 + l15)*1536 + 512 + h*64;
  #pragma unroll
  for (int kh=0;kh<2;kh++){
    bf16x8 a = *(const bf16x8*)(abase + kh*32 + l4*8);
    #pragma unroll
    for (int ct=0;ct<18;ct++){
      bf16x8 bb = *(const bf16x8*)(pmb + (ct*16+l15)*64 + kh*32 + l4*8);
      acc[ct] = MFMA16(a, bb, acc[ct]);
    }
  }
  float mx = -3e38f;
  #pragma unroll
  for (int ct=0;ct<18;ct++){
    if (ct*16 + l15 < 266){
      #pragma unroll
      for (int r=0;r<4;r++) mx = fmaxf(mx, acc[ct][r]);
    }
  }
  #pragma unroll
  for (int o=32;o>0;o>>=1) mx = fmaxf(mx, __shfl_xor(mx, o));
  __shared__ float red[4];
  if (lane==0) red[wid] = mx;
  __syncthreads();
  if (t==0){
    float m2 = fmaxf(fmaxf(red[0],red[1]),fmaxf(red[2],red[3]));
    atomicMax(mxk + bh, encf(m2));
  }
}

// kp = ratio*(exp(dd - diag - MX)+eps) written DIRECTLY transposed to
// kpT[bhl][MPAD m][4096 n]; diag computed in-kernel from the same fragments.
// grid (64, KG), block 256
__global__ __launch_bounds__(256,2)
void favor_kp(const bf16_t* __restrict__ qkv, const bf16_t* __restrict__ pmb,
              const unsigned* __restrict__ mxk, bf16_t* __restrict__ kpT, int bh0)
{
  int bhl = blockIdx.y, bh = bh0 + bhl, b = bh>>3, h = bh&7;
  int t = threadIdx.x, wid = t>>6, lane = t&63;
  int l15 = lane&15, l4 = lane>>4;
  int n0 = blockIdx.x*64, row0 = wid*16;
  f32x4 acc[18];
  #pragma unroll
  for (int c=0;c<18;c++) acc[c] = f32x4{0.f,0.f,0.f,0.f};
  const bf16_t* abase = qkv + ((size_t)(b*4096) + n0 + row0 + l15)*1536 + 512 + h*64;
  float rsq = 0.f;
  #pragma unroll
  for (int kh=0;kh<2;kh++){
    bf16x8 a = *(const bf16x8*)(abase + kh*32 + l4*8);
    #pragma unroll
    for (int e=0;e<8;e++){ float v = b2f((bf16_t)a[e]); rsq += v*v; }
    #pragma unroll
    for (int ct=0;ct<18;ct++){
      bf16x8 bb = *(const bf16x8*)(pmb + (ct*16+l15)*64 + kh*32 + l4*8);
      acc[ct] = MFMA16(a, bb, acc[ct]);
    }
  }
  rsq += __shfl_xor(rsq, 16);
  rsq += __shfl_xor(rsq, 32);                 // lanes sharing l15: full row sumsq
  float MX = decf(mxk[bh]);
  constexpr float DSC = 0.5f*DN_SCALE*DN_SCALE;
  float dg[4];
  #pragma unroll
  for (int r=0;r<4;r++) dg[r] = DSC * __shfl(rsq, l4*4 + r);
  #pragma unroll
  for (int ct=0;ct<18;ct++){
    int col = ct*16 + l15;
    ushort4 o;
    if (col < 266){
      o.x = f2b(RATIO*(__expf(acc[ct][0] - dg[0] - MX) + KEPS));
      o.y = f2b(RATIO*(__expf(acc[ct][1] - dg[1] - MX) + KEPS));
      o.z = f2b(RATIO*(__expf(acc[ct][2] - dg[2] - MX) + KEPS));
      o.w = f2b(RATIO*(__expf(acc[ct][3] - dg[3] - MX) + KEPS));
    } else { o.x=0; o.y=0; o.z=0; o.w=0; }
    *(ushort4*)(kpT + ((size_t)bhl*MPAD + col)*4096 + n0 + row0 + l4*4) = o;
  }
}

// ctx partial GEMM (K-split x4) with fused partial ksum. grid (17, 4, KG).
__global__ __launch_bounds__(256,2)
void ctx_gemm(const bf16_t* __restrict__ kpT, const bf16_t* __restrict__ vT,
              float* __restrict__ ctxP, float* __restrict__ ksumP, int bh0)
{
  int m0 = blockIdx.x*16, ks = blockIdx.y, bhl = blockIdx.z, bh = bh0 + bhl;
  int t = threadIdx.x, wid = t>>6, lane = t&63;
  int l15 = lane&15, l4 = lane>>4;
  f32x4 acc[4];
  #pragma unroll
  for (int c=0;c<4;c++) acc[c] = f32x4{0.f,0.f,0.f,0.f};
  const bf16_t* Abase = kpT + ((size_t)bhl*MPAD + m0 + l15)*4096;
  const bf16_t* Bbase = vT + ((size_t)bh*64)*4096;
  const int kb = ks*1024 + wid*256;
  float ksp = 0.f;
  for (int k = kb; k < kb + 256; k += 32){
    bf16x8 a = *(const bf16x8*)(Abase + k + l4*8);
    #pragma unroll
    for (int e=0;e<8;e++) ksp += b2f((bf16_t)a[e]);
    #pragma unroll
    for (int ct=0;ct<4;ct++){
      bf16x8 bb = *(const bf16x8*)(Bbase + (size_t)(ct*16+l15)*4096 + k + l4*8);
      acc[ct] = MFMA16(a, bb, acc[ct]);
    }
  }
  // row-sum partials: combine the 4 lanes sharing l15
  ksp += __shfl_xor(ksp, 16);
  ksp += __shfl_xor(ksp, 32);
  __shared__ float red[4][4][16][16];
  __shared__ float ksred[4][16];
  if (l4 == 0) ksred[wid][l15] = ksp;
  #pragma unroll
  for (int ct=0;ct<4;ct++)
    #pragma unroll
    for (int r=0;r<4;r++) red[wid][ct][l4*4+r][l15] = acc[ct][r];
  __syncthreads();
  #pragma unroll
  for (int i=0;i<4;i++){
    int e = i*256 + t;
    int ct = e>>8, row = (e>>4)&15, col = e&15;
    float s = ((red[0][ct][row][col] + red[1][ct][row][col])
             + (red[2][ct][row][col] + red[3][ct][row][col]));
    ctxP[(((size_t)bhl*4 + ks)*272 + m0 + row)*64 + ct*16 + col] = s;
  }
  if (t < 16){
    float s2 = ksred[0][t] + ksred[1][t] + ksred[2][t] + ksred[3][t];
    ksumP[((size_t)bhl*4 + ks)*272 + m0 + t] = s2;
  }
}

// reduce K-split partials -> ctxT[bh][d][MPAD m] bf16 (zero pad m>=272) and
// ksumf[bh][m].  grid (72, KG)
__global__ __launch_bounds__(256)
void ctx_reduce(const float* __restrict__ ctxP, const float* __restrict__ ksumP,
                bf16_t* __restrict__ ctxT, float* __restrict__ ksumf, int bh0)
{
  int bhl = blockIdx.y, bh = bh0 + bhl;
  int idx = blockIdx.x*256 + threadIdx.x;   // < 18432 = 288*64
  int m = idx>>6, d = idx&63;
  float s = 0.f;
  if (m < 272){
    #pragma unroll
    for (int ks=0;ks<4;ks++)
      s += ctxP[(((size_t)bhl*4 + ks)*272 + m)*64 + d];
  }
  ctxT[((size_t)bh*64 + d)*MPAD + m] = f2b(s);
  if (idx < 272){
    float s2 = 0.f;
    #pragma unroll
    for (int ks=0;ks<4;ks++)
      s2 += ksumP[(((size_t)bhl*4 + ks)*272) + idx];
    ksumf[(size_t)bh*MPAD + idx] = s2;
  }
}

// fused q-side: dd MFMA -> in-kernel diag -> rowmax -> qp -> LDS ->
// out MFMA * dinv -> attn. grid (64, 32), block 256
__global__ __launch_bounds__(256,2)
void favor_q(const bf16_t* __restrict__ qkv, const bf16_t* __restrict__ pmb,
             const float* __restrict__ ksumf,
             const bf16_t* __restrict__ ctxT, bf16_t* __restrict__ attn)
{
  __shared__ alignas(16) ushort qpLds[64*296];
  __shared__ float ksLds[288];
  int bh = blockIdx.y, b = bh>>3, h = bh&7;
  int t = threadIdx.x, wid = t>>6, lane = t&63;
  int l15 = lane&15, l4 = lane>>4;
  int n0 = blockIdx.x*64, row0 = wid*16;
  ksLds[t] = (t < 272) ? ksumf[(size_t)bh*MPAD + t] : 0.f;
  if (t < 32) ksLds[256+t] = (256+t < 272) ? ksumf[(size_t)bh*MPAD + 256 + t] : 0.f;
  __syncthreads();

  f32x4 acc[18];
  #pragma unroll
  for (int c=0;c<18;c++) acc[c] = f32x4{0.f,0.f,0.f,0.f};
  const bf16_t* abase = qkv + ((size_t)(b*4096) + n0 + row0 + l15)*1536 + h*64;
  float rsq = 0.f;
  #pragma unroll
  for (int kh=0;kh<2;kh++){
    bf16x8 a = *(const bf16x8*)(abase + kh*32 + l4*8);
    #pragma unroll
    for (int e=0;e<8;e++){ float v = b2f((bf16_t)a[e]); rsq += v*v; }
    #pragma unroll
    for (int ct=0;ct<18;ct++){
      bf16x8 bb = *(const bf16x8*)(pmb + (ct*16+l15)*64 + kh*32 + l4*8);
      acc[ct] = MFMA16(a, bb, acc[ct]);
    }
  }
  rsq += __shfl_xor(rsq, 16);
  rsq += __shfl_xor(rsq, 32);
  constexpr float DSC = 0.5f*DN_SCALE*DN_SCALE;
  float dg[4];
  #pragma unroll
  for (int r=0;r<4;r++) dg[r] = DSC * __shfl(rsq, l4*4 + r);

  // per-row max over valid cols
  float mxr[4] = {-3e38f,-3e38f,-3e38f,-3e38f};
  #pragma unroll
  for (int ct=0;ct<18;ct++){
    if (ct*16 + l15 < 266){
      #pragma unroll
      for (int r=0;r<4;r++) mxr[r] = fmaxf(mxr[r], acc[ct][r]);
    }
  }
  #pragma unroll
  for (int r=0;r<4;r++){
    mxr[r] = fmaxf(mxr[r], __shfl_xor(mxr[r], 1));
    mxr[r] = fmaxf(mxr[r], __shfl_xor(mxr[r], 2));
    mxr[r] = fmaxf(mxr[r], __shfl_xor(mxr[r], 4));
    mxr[r] = fmaxf(mxr[r], __shfl_xor(mxr[r], 8));
  }
  float den[4] = {0.f,0.f,0.f,0.f};
  #pragma unroll
  for (int ct=0;ct<18;ct++){
    int col = ct*16 + l15;
    float ks = ksLds[col];
    #pragma unroll
    for (int r=0;r<4;r++){
      float qpv = 0.f;
      if (col < 266){
        qpv = RATIO*(__expf(acc[ct][r] - dg[r] - mxr[r]) + KEPS);
        den[r] += qpv*ks;
      }
      qpLds[(row0 + l4*4 + r)*296 + col] = f2b(qpv);
    }
  }
  float dinv[4];
  #pragma unroll
  for (int r=0;r<4;r++){
    den[r] += __shfl_xor(den[r], 1);
    den[r] += __shfl_xor(den[r], 2);
    den[r] += __shfl_xor(den[r], 4);
    den[r] += __shfl_xor(den[r], 8);
    dinv[r] = 1.0f/den[r];
  }
  __syncthreads();

  f32x4 o2[4];
  #pragma unroll
  for (int c=0;c<4;c++) o2[c] = f32x4{0.f,0.f,0.f,0.f};
  const bf16_t* Bbase = ctxT + (size_t)bh*64*MPAD;
  #pragma unroll
  for (int kk=0;kk<9;kk++){
    int k0 = kk*32;
    bf16x8 a = *(const bf16x8*)&qpLds[(row0 + l15)*296 + k0 + l4*8];
    #pragma unroll
    for (int ct=0;ct<4;ct++){
      bf16x8 bb = *(const bf16x8*)(Bbase + (size_t)(ct*16+l15)*MPAD + k0 + l4*8);
      o2[ct] = MFMA16(a, bb, o2[ct]);
    }
  }
  #pragma unroll
  for (int ct=0;ct<4;ct++)
    #pragma unroll
    for (int r=0;r<4;r++)
      attn[((size_t)(b*4096) + n0 + row0 + l4*4 + r)*512 + h*64 + ct*16 + l15]
        = f2b(o2[ct][r] * dinv[r]);
}

// ---------------------------------------------------------------- launcher
extern "C" void kernel_launch(void* const* d_in, const int* in_sizes, int n_in,
                              void* d_out, int out_size, void* d_ws, size_t ws_size,
                              hipStream_t stream)
{
  (void)in_sizes; (void)n_in; (void)out_size;
  const float* x      = (const float*)d_in[0];
  const float* proj_w = (const float*)d_in[1];
  const float* proj_b = (const float*)d_in[2];
  const float* ln1_g  = (const float*)d_in[3];
  const float* ln1_b  = (const float*)d_in[4];
  const float* wq     = (const float*)d_in[5];
  const float* bq     = (const float*)d_in[6];
  const float* wk     = (const float*)d_in[7];
  const float* bk     = (const float*)d_in[8];
  const float* wv     = (const float*)d_in[9];
  const float* bv     = (const float*)d_in[10];
  const float* wo     = (const float*)d_in[11];
  const float* bo     = (const float*)d_in[12];
  const float* pm     = (const float*)d_in[13];
  const float* ln2_g  = (const float*)d_in[14];
  const float* ln2_b  = (const float*)d_in[15];
  const float* w1     = (const float*)d_in[16];
  const float* b1     = (const float*)d_in[17];
  const float* w2     = (const float*)d_in[18];
  const float* b2     = (const float*)d_in[19];
  float* out = (float*)d_out;
  const size_t MB = 1ull<<20;

  char* ws = (char*)d_ws;
  size_t off = 0;
  auto alloc = [&](size_t bytes)->void*{ void* p = ws + off; off += (bytes + 255) & ~(size_t)255; return p; };
  bf16_t* Wt_proj = (bf16_t*)alloc(2ul*1024*1024);
  bf16_t* Wt_qkv  = (bf16_t*)alloc(2ul*1536*1024);
  bf16_t* Wt_o    = (bf16_t*)alloc(2ul*1024*512);
  bf16_t* Wt_1    = (bf16_t*)alloc(2ul*4096*1024);
  bf16_t* Wt_2    = (bf16_t*)alloc(2ul*1024*4096);
  float*  bqkv    = (float*) alloc(4ul*1536);
  unsigned* mxk   = (unsigned*)alloc(4ul*32);
  bf16_t* pmb     = (bf16_t*)alloc(2ul*MPAD*64);
  float*  ksumf   = (float*) alloc(4ul*32*MPAD);
  bf16_t* ctxT    = (bf16_t*)alloc(2ul*32*64*MPAD);
  float*  ctxP    = (float*) alloc(4ul*8*4*272*64);   // K-split partials (KG<=8)
  float*  ksumP   = (float*) alloc(4ul*8*4*272);
  char*   R       = (char*)  alloc(0);
  size_t R_avail = (ws_size > off) ? ws_size - off : 0;

  // region floor: phase A 64MB, k-side KG=4 ~58MB, ff NC=4 50MB
  if (R_avail < 67*MB){ zero_out<<<dim3(65536), 256, 0, stream>>>(out, 16777216L); return; }
  int KG = (R_avail >= 87*MB) ? 8 : 4;    // k-side top: 48 + KG*2.36MB
  int NC = (R_avail >= 84*MB) ? 2 : 4;    // ff top: 16 + (16384/NC)*8KB

  // R overlays (stream-serialized disjoint lifetimes)
  bf16_t* qkv  = (bf16_t*)(R);               // 48MB   [LN1/qkv .. favor_q]
  bf16_t* h1c  = (bf16_t*)(R + 48*MB);       // 16MB   [phase A]
  bf16_t* kpT  = (bf16_t*)(R + 48*MB);       // KG*2.36MB [k-side]
  bf16_t* attn = (bf16_t*)(R + 48*MB);       // 16MB   [favor_q .. wo]
  long    CH   = 16384/NC;
  bf16_t* h2c  = (bf16_t*)(R);               // reused as xbc too
  bf16_t* ff1c = (bf16_t*)(R + 16*MB);       // CH*8KB
  bf16_t* vT   = (bf16_t*)d_out;             // 16.8MB scratch in d_out (dead till wo)

  // 1) weights -> bf16 transposed, pm cast
  wt_cast<<<dim3(32,32), 256, 0, stream>>>(proj_w, Wt_proj, 1024, 1024);
  wt_cast<<<dim3(32,16), 256, 0, stream>>>(wq, Wt_qkv,              1024, 512);
  wt_cast<<<dim3(32,16), 256, 0, stream>>>(wk, Wt_qkv + 512*1024,   1024, 512);
  wt_cast<<<dim3(32,16), 256, 0, stream>>>(wv, Wt_qkv + 1024*1024,  1024, 512);
  wt_cast<<<dim3(16,32), 256, 0, stream>>>(wo, Wt_o, 512, 1024);
  wt_cast<<<dim3(32,128),256, 0, stream>>>(w1, Wt_1, 1024, 4096);
  wt_cast<<<dim3(128,32),256, 0, stream>>>(w2, Wt_2, 4096, 1024);
  concat_bias<<<dim3(6), 256, 0, stream>>>(bq, bk, bv, bqkv);
  pm_cast<<<dim3(72), 256, 0, stream>>>(pm, pmb);

  // 2) phase A: LN1 + qkv GEMM, 2 chunks of 8192 rows (L2-resident staging)
  for (int c = 0; c < 2; c++){
    ln_kernel<<<dim3(8192), 256, 0, stream>>>(x + (size_t)c*8192*1024, ln1_g, ln1_b, h1c);
    gemm_bt<0,0,0,1><<<dim3(12,64), 256, 0, stream>>>(h1c, 1024, Wt_qkv, 1024,
        bqkv, nullptr, nullptr, qkv + (size_t)c*8192*1536, 1536, 1024);
  }

  // 3) FAVOR
  vt_trans<<<dim3(128,64), 256, 0, stream>>>(qkv, vT);
  mx_init<<<dim3(1), 64, 0, stream>>>(mxk);
  favor_kmax2<<<dim3(64,32), 256, 0, stream>>>(qkv, pmb, mxk);
  for (int g = 0; g < 32; g += KG){
    favor_kp<<<dim3(64,KG), 256, 0, stream>>>(qkv, pmb, mxk, kpT, g);
    ctx_gemm<<<dim3(17,4,KG), 256, 0, stream>>>(kpT, vT, ctxP, ksumP, g);
    ctx_reduce<<<dim3(72,KG), 256, 0, stream>>>(ctxP, ksumP, ctxT, ksumf, g);
  }
  favor_q<<<dim3(64,32), 256, 0, stream>>>(qkv, pmb, ksumf, ctxT, attn);

  // 4) x2 = x + attn @ wo + bo -> d_out (f32); overwrites vT scratch
  gemm_bt<1,0,0,0><<<dim3(8,128), 256, 0, stream>>>(attn, 512, Wt_o, 512,
      bo, x, nullptr, out, 1024, 512);

  // 5) per chunk: LN2 -> ff1(gelu) -> ff2(+res, in-place) -> gate(in-place)
  for (int c = 0; c < NC; c++){
    float* xrow = out + (size_t)c*CH*1024;
    ln_kernel<<<dim3((unsigned)CH), 256, 0, stream>>>(xrow, ln2_g, ln2_b, h2c);
    gemm_bt<0,1,0,1><<<dim3(32,(unsigned)(CH/128)), 256, 0, stream>>>(h2c, 1024, Wt_1, 1024,
        b1, nullptr, nullptr, ff1c, 4096, 1024);
    gemm_bt<1,0,0,0><<<dim3(8,(unsigned)(CH/128)), 256, 0, stream>>>(ff1c, 4096, Wt_2, 4096,
        b2, xrow, nullptr, xrow, 1024, 4096);
    cast_f32_bf16<<<dim3((unsigned)CH), 256, 0, stream>>>(x + (size_t)c*CH*1024, h2c);
    gemm_bt<0,0,1,0><<<dim3(8,(unsigned)(CH/128)), 256, 0, stream>>>(h2c, 1024, Wt_proj, 1024,
        proj_b, nullptr, xrow, xrow, 1024, 1024);
  }
}

// Round 15
// 923.926 us; speedup vs baseline: 1.0991x; 1.0094x over previous
//
#include <hip/hip_runtime.h>
#include <math.h>

typedef unsigned short bf16_t;
using bf16x8 = __attribute__((ext_vector_type(8))) short;
using f32x4  = __attribute__((ext_vector_type(4))) float;

#define DEVFN static __device__ __forceinline__

DEVFN float b2f(bf16_t u){ unsigned v=((unsigned)u)<<16; float f; __builtin_memcpy(&f,&v,4); return f; }
DEVFN bf16_t f2b(float f){ unsigned u; __builtin_memcpy(&u,&f,4); u += 0x7fffu + ((u>>16)&1u); return (bf16_t)(u>>16); }
DEVFN unsigned encf(float f){ unsigned u=__float_as_uint(f); return (u&0x80000000u)? ~u : (u|0x80000000u); }
DEVFN float decf(unsigned e){ return __uint_as_float((e&0x80000000u)? (e^0x80000000u) : ~e); }

// erf via Abramowitz-Stegun 7.1.26, |abs err| <= 1.5e-7
DEVFN float erf_fast(float x){
  float ax = fabsf(x);
  float t = __builtin_amdgcn_rcpf(1.0f + 0.3275911f*ax);
  float y = t*(0.254829592f + t*(-0.284496736f + t*(1.421413741f
          + t*(-1.453152027f + t*1.061405429f))));
  float r = 1.0f - y*__expf(-ax*ax);
  return copysignf(r, x);
}

constexpr float DN_SCALE = 0.35355339059327373f;   // 64^-0.25
constexpr float RATIO    = 0.06131393394849658f;   // 266^-0.5
constexpr float KEPS     = 1e-4f;
#define MPAD 288   // 266 features padded to 9*32

#define GLOAD_LDS16(g, l) __builtin_amdgcn_global_load_lds( \
    (__attribute__((address_space(1))) void*)(g), \
    (__attribute__((address_space(3))) void*)(l), 16, 0, 0)

#define MFMA16(a,b,c) __builtin_amdgcn_mfma_f32_16x16x32_bf16(a,b,c,0,0,0)

// ------------------------------------------------ weight transpose + cast
__global__ __launch_bounds__(256)
void wt_cast(const float* __restrict__ W, bf16_t* __restrict__ Wt, int K, int N)
{
  __shared__ alignas(16) float ts[32][33];
  int t = threadIdx.x;
  int r = t>>3, c4 = (t&7)*4;
  int k0 = blockIdx.x*32, n0 = blockIdx.y*32;
  float4 v = *(const float4*)(W + (size_t)(k0+r)*N + n0 + c4);
  ts[r][c4+0]=v.x; ts[r][c4+1]=v.y; ts[r][c4+2]=v.z; ts[r][c4+3]=v.w;
  __syncthreads();
  ushort4 o;
  o.x = f2b(ts[c4+0][r]); o.y = f2b(ts[c4+1][r]);
  o.z = f2b(ts[c4+2][r]); o.w = f2b(ts[c4+3][r]);
  *(ushort4*)(Wt + (size_t)(n0+r)*K + k0 + c4) = o;
}

__global__ __launch_bounds__(256)
void concat_bias(const float* __restrict__ bq, const float* __restrict__ bk,
                 const float* __restrict__ bv, float* __restrict__ dst)
{
  int t = blockIdx.x*256 + threadIdx.x;
  if (t < 512) dst[t] = bq[t];
  else if (t < 1024) dst[t] = bk[t-512];
  else dst[t] = bv[t-1024];
}

__global__ void mx_init(unsigned* m){ if (threadIdx.x < 32) m[threadIdx.x] = 0u; }

__global__ void zero_out(float* o, long n){
  long i = (long)blockIdx.x*256 + threadIdx.x;
  if (i < n) o[i] = 0.f;
}

// pmb[m][64] bf16 = pm * dn, zero-padded rows 266..287
__global__ __launch_bounds__(256)
void pm_cast(const float* __restrict__ pm, bf16_t* __restrict__ pmb)
{
  int idx = blockIdx.x*256 + threadIdx.x;      // grid 72 -> 18432
  int r = idx>>6, c = idx&63;
  pmb[idx] = (r < 266) ? f2b(pm[r*64+c]*DN_SCALE) : (bf16_t)0;
}

// v transpose: qkv v-part -> vT[bh*64+d][4096]. grid (128, 64), block 256
__global__ __launch_bounds__(256)
void vt_trans(const bf16_t* __restrict__ qkv, bf16_t* __restrict__ vT)
{
  __shared__ ushort ts[32][36];
  int by = blockIdx.y;
  int bh = by>>1, dt = by&1, b = bh>>3, h = bh&7;
  int n0 = blockIdx.x*32;
  int t = threadIdx.x, r = t>>3, c4 = (t&7)*4;
  ushort4 v = *(const ushort4*)(qkv + ((size_t)b*4096 + n0 + r)*1536 + 1024 + h*64 + dt*32 + c4);
  ts[r][c4+0]=v.x; ts[r][c4+1]=v.y; ts[r][c4+2]=v.z; ts[r][c4+3]=v.w;
  __syncthreads();
  ushort4 o;
  o.x = ts[c4+0][r]; o.y = ts[c4+1][r]; o.z = ts[c4+2][r]; o.w = ts[c4+3][r];
  *(ushort4*)(vT + ((size_t)bh*64 + dt*32 + r)*4096 + n0 + c4) = o;
}

// ---------------------------------------------------------------- LayerNorm
__global__ __launch_bounds__(256)
void ln_kernel(const float* __restrict__ x, const float* __restrict__ g,
               const float* __restrict__ b, bf16_t* __restrict__ out)
{
  long row = blockIdx.x; int t = threadIdx.x;
  float4 v = ((const float4*)x)[row*256 + t];
  float s = v.x+v.y+v.z+v.w;
  #pragma unroll
  for (int o=32;o>0;o>>=1) s += __shfl_xor(s, o);
  __shared__ float r1[4], r2[4];
  if ((t&63)==0) r1[t>>6] = s;
  __syncthreads();
  float mu = (r1[0]+r1[1]+r1[2]+r1[3]) * (1.f/1024.f);
  float dx = v.x-mu, dy = v.y-mu, dz = v.z-mu, dw = v.w-mu;
  float ss = dx*dx+dy*dy+dz*dz+dw*dw;
  #pragma unroll
  for (int o=32;o>0;o>>=1) ss += __shfl_xor(ss, o);
  if ((t&63)==0) r2[t>>6] = ss;
  __syncthreads();
  float var = (r2[0]+r2[1]+r2[2]+r2[3]) * (1.f/1024.f);
  float rs = rsqrtf(var + 1e-5f);
  float4 gg = ((const float4*)g)[t], bb = ((const float4*)b)[t];
  ushort4 o4;
  o4.x = f2b(dx*rs*gg.x+bb.x); o4.y = f2b(dy*rs*gg.y+bb.y);
  o4.z = f2b(dz*rs*gg.z+bb.z); o4.w = f2b(dw*rs*gg.w+bb.w);
  ((ushort4*)out)[row*256+t] = o4;
}

// f32 -> bf16 cast, grid = rows (of 1024)
__global__ __launch_bounds__(256)
void cast_f32_bf16(const float* __restrict__ in, bf16_t* __restrict__ out)
{
  long i = (long)blockIdx.x*256 + threadIdx.x;
  float4 v = ((const float4*)in)[i];
  ushort4 o;
  o.x = f2b(v.x); o.y = f2b(v.y); o.z = f2b(v.z); o.w = f2b(v.w);
  ((ushort4*)out)[i] = o;
}

// ---------------------------------------------------------------- GEMM (bf16 MFMA)
// 128x128 tile, BK=32, 4 waves, double-buffered LDS (2-phase: stage tile t+1
// BEFORE computing tile t; one __syncthreads per step).  PROVEN OPTIMUM here:
// manual vmcnt/raw-barrier variants all measured slower (R6/R8/R10); larger
// staging chunks break L2 residency (R12).  XCD-bijective chunking +
// 16-row supertile block remap for L2 locality (requires nwg%8==0, Mtiles%16==0).
template<int RES, int GELU, int GATEF, int OBF>
__global__ __launch_bounds__(256)
void gemm_bt(const bf16_t* __restrict__ A, int lda,
             const bf16_t* __restrict__ Bt, int ldb,
             const float* __restrict__ bias,
             const float* res,
             const float* gatef,
             void* Cout, int N, int K)
{
  __shared__ alignas(16) bf16_t As[2][128*32];
  __shared__ alignas(16) bf16_t Bs[2][128*32];
  const int tid = threadIdx.x;
  const int wid = tid>>6, lane = tid&63;
  const int l15 = lane&15, l4 = lane>>4;
  const int wm = wid>>1, wn = wid&1;

  // ---- block remap: XCD-contiguous chunks over a ty-fast supertiled order
  const int NX = gridDim.x;
  const int nwg = NX * gridDim.y;
  const int lid = blockIdx.y*NX + blockIdx.x;
  const int qc = nwg>>3;
  const int wgid = (lid&7)*qc + (lid>>3);          // nwg%8==0 bijective chunk
  const int stripe = wgid / (16*NX);
  const int rem    = wgid % (16*NX);
  const long m0 = (long)(stripe*16 + (rem & 15))*128;
  const long n0 = (long)(rem >> 4)*128;

  f32x4 acc[4][4];
  #pragma unroll
  for (int i=0;i<4;i++)
    #pragma unroll
    for (int j=0;j<4;j++) acc[i][j] = f32x4{0.f,0.f,0.f,0.f};

  const bf16_t* ga = A  + (size_t)(m0 + (tid>>2))*lda + (tid&3)*8;
  const bf16_t* gb = Bt + (size_t)(n0 + (tid>>2))*ldb + (tid&3)*8;

  auto STAGE = [&](int buf){
    GLOAD_LDS16(ga,                   &As[buf][wid*512]);
    GLOAD_LDS16(ga + (size_t)64*lda,  &As[buf][2048 + wid*512]);
    GLOAD_LDS16(gb,                   &Bs[buf][wid*512]);
    GLOAD_LDS16(gb + (size_t)64*ldb,  &Bs[buf][2048 + wid*512]);
    ga += 32; gb += 32;
  };

  const int nt = K >> 5;
  STAGE(0);
  __syncthreads();                      // drains vmcnt(0): tile 0 resident
  int cur = 0;
  for (int t = 0; t < nt; ++t){
    if (t+1 < nt) STAGE(cur^1);         // issue next-tile loads FIRST
    bf16x8 af[4], bfr[4];
    #pragma unroll
    for (int i=0;i<4;i++){
      af[i]  = *(const bf16x8*)(&As[cur][(wm*64 + i*16 + l15)*32 + l4*8]);
      bfr[i] = *(const bf16x8*)(&Bs[cur][(wn*64 + i*16 + l15)*32 + l4*8]);
    }
    #pragma unroll
    for (int i=0;i<4;i++)
      #pragma unroll
      for (int j=0;j<4;j++)
        acc[i][j] = MFMA16(af[i], bfr[j], acc[i][j]);
    __syncthreads();                    // drains vmcnt(0): next tile resident,
    cur ^= 1;                           // and all reads of As[cur] complete
  }

  #pragma unroll
  for (int i=0;i<4;i++){
    #pragma unroll
    for (int j=0;j<4;j++){
      #pragma unroll
      for (int r=0;r<4;r++){
        long row = m0 + wm*64 + i*16 + l4*4 + r;
        long col = n0 + wn*64 + j*16 + l15;
        float v = acc[i][j][r] + bias[col];
        if constexpr (RES)   v += res[row*(long)N + col];
        if constexpr (GELU)  v = 0.5f*v*(1.0f + erf_fast(v*0.70710678118654752f));
        if constexpr (GATEF) v *= gatef[row*(long)N + col];
        if constexpr (OBF)  ((bf16_t*)Cout)[row*(long)N + col] = f2b(v);
        else                ((float* )Cout)[row*(long)N + col] = v;
      }
    }
  }
}

// ---------------------------------------------------------------- FAVOR (MFMA)
// qkv: [16384][1536] bf16, q @ h*64, k @ 512+h*64, v @ 1024+h*64.

// dd-max over all (n,m) per bh. grid (64, 32), block 256 (4 waves x 16 rows)
__global__ __launch_bounds__(256,2)
void favor_kmax2(const bf16_t* __restrict__ qkv, const bf16_t* __restrict__ pmb,
                 unsigned* __restrict__ mxk)
{
  int bh = blockIdx.y, b = bh>>3, h = bh&7;
  int t = threadIdx.x, wid = t>>6, lane = t&63;
  int l15 = lane&15, l4 = lane>>4;
  int n0 = blockIdx.x*64, row0 = wid*16;
  f32x4 acc[18];
  #pragma unroll
  for (int c=0;c<18;c++) acc[c] = f32x4{0.f,0.f,0.f,0.f};
  const bf16_t* abase = qkv + ((size_t)(b*4096) + n0 + row0 + l15)*1536 + 512 + h*64;
  #pragma unroll
  for (int kh=0;kh<2;kh++){
    bf16x8 a = *(const bf16x8*)(abase + kh*32 + l4*8);
    #pragma unroll
    for (int ct=0;ct<18;ct++){
      bf16x8 bb = *(const bf16x8*)(pmb + (ct*16+l15)*64 + kh*32 + l4*8);
      acc[ct] = MFMA16(a, bb, acc[ct]);
    }
  }
  float mx = -3e38f;
  #pragma unroll
  for (int ct=0;ct<18;ct++){
    if (ct*16 + l15 < 266){
      #pragma unroll
      for (int r=0;r<4;r++) mx = fmaxf(mx, acc[ct][r]);
    }
  }
  #pragma unroll
  for (int o=32;o>0;o>>=1) mx = fmaxf(mx, __shfl_xor(mx, o));
  __shared__ float red[4];
  if (lane==0) red[wid] = mx;
  __syncthreads();
  if (t==0){
    float m2 = fmaxf(fmaxf(red[0],red[1]),fmaxf(red[2],red[3]));
    atomicMax(mxk + bh, encf(m2));
  }
}

// kp = ratio*(exp(dd - diag - MX)+eps) -> kpT[bhl][MPAD m][4096 n], staged
// through LDS for coalesced 128B row-segment writes.  grid (64, KG), block 256
__global__ __launch_bounds__(256,2)
void favor_kp(const bf16_t* __restrict__ qkv, const bf16_t* __restrict__ pmb,
              const unsigned* __restrict__ mxk, bf16_t* __restrict__ kpT, int bh0)
{
  __shared__ ushort ts[288][68];   // [m][n-local], +4 pad: 2-way max bank alias
  int bhl = blockIdx.y, bh = bh0 + bhl, b = bh>>3, h = bh&7;
  int t = threadIdx.x, wid = t>>6, lane = t&63;
  int l15 = lane&15, l4 = lane>>4;
  int n0 = blockIdx.x*64, row0 = wid*16;
  f32x4 acc[18];
  #pragma unroll
  for (int c=0;c<18;c++) acc[c] = f32x4{0.f,0.f,0.f,0.f};
  const bf16_t* abase = qkv + ((size_t)(b*4096) + n0 + row0 + l15)*1536 + 512 + h*64;
  float rsq = 0.f;
  #pragma unroll
  for (int kh=0;kh<2;kh++){
    bf16x8 a = *(const bf16x8*)(abase + kh*32 + l4*8);
    #pragma unroll
    for (int e=0;e<8;e++){ float v = b2f((bf16_t)a[e]); rsq += v*v; }
    #pragma unroll
    for (int ct=0;ct<18;ct++){
      bf16x8 bb = *(const bf16x8*)(pmb + (ct*16+l15)*64 + kh*32 + l4*8);
      acc[ct] = MFMA16(a, bb, acc[ct]);
    }
  }
  rsq += __shfl_xor(rsq, 16);
  rsq += __shfl_xor(rsq, 32);                 // lanes sharing l15: full row sumsq
  float MX = decf(mxk[bh]);
  constexpr float DSC = 0.5f*DN_SCALE*DN_SCALE;
  float dg[4];
  #pragma unroll
  for (int r=0;r<4;r++) dg[r] = DSC * __shfl(rsq, l4*4 + r);
  #pragma unroll
  for (int ct=0;ct<18;ct++){
    int col = ct*16 + l15;
    ushort4 o;
    if (col < 266){
      o.x = f2b(RATIO*(__expf(acc[ct][0] - dg[0] - MX) + KEPS));
      o.y = f2b(RATIO*(__expf(acc[ct][1] - dg[1] - MX) + KEPS));
      o.z = f2b(RATIO*(__expf(acc[ct][2] - dg[2] - MX) + KEPS));
      o.w = f2b(RATIO*(__expf(acc[ct][3] - dg[3] - MX) + KEPS));
    } else { o.x=0; o.y=0; o.z=0; o.w=0; }
    *(ushort4*)&ts[col][row0 + l4*4] = o;
  }
  __syncthreads();
  // write-out: 8 lanes x 16B = coalesced 128B per m-row; 32 rows/iter x 9
  int lr = lane>>3, cc = lane&7;
  #pragma unroll
  for (int it=0; it<9; ++it){
    int m = it*32 + wid*8 + lr;
    ushort4 w0 = *(ushort4*)&ts[m][cc*8];
    ushort4 w1 = *(ushort4*)&ts[m][cc*8+4];
    bf16_t* dst = kpT + ((size_t)bhl*MPAD + m)*4096 + n0 + cc*8;
    *(ushort4*)(dst)   = w0;
    *(ushort4*)(dst+4) = w1;
  }
}

// ctx partial GEMM (K-split x8 for occupancy) with fused partial ksum.
// grid (17, 8, KG), block 256
__global__ __launch_bounds__(256,2)
void ctx_gemm(const bf16_t* __restrict__ kpT, const bf16_t* __restrict__ vT,
              float* __restrict__ ctxP, float* __restrict__ ksumP, int bh0)
{
  int m0 = blockIdx.x*16, ks = blockIdx.y, bhl = blockIdx.z, bh = bh0 + bhl;
  int t = threadIdx.x, wid = t>>6, lane = t&63;
  int l15 = lane&15, l4 = lane>>4;
  f32x4 acc[4];
  #pragma unroll
  for (int c=0;c<4;c++) acc[c] = f32x4{0.f,0.f,0.f,0.f};
  const bf16_t* Abase = kpT + ((size_t)bhl*MPAD + m0 + l15)*4096;
  const bf16_t* Bbase = vT + ((size_t)bh*64)*4096;
  const int kb = ks*512 + wid*128;
  float ksp = 0.f;
  for (int k = kb; k < kb + 128; k += 32){
    bf16x8 a = *(const bf16x8*)(Abase + k + l4*8);
    #pragma unroll
    for (int e=0;e<8;e++) ksp += b2f((bf16_t)a[e]);
    #pragma unroll
    for (int ct=0;ct<4;ct++){
      bf16x8 bb = *(const bf16x8*)(Bbase + (size_t)(ct*16+l15)*4096 + k + l4*8);
      acc[ct] = MFMA16(a, bb, acc[ct]);
    }
  }
  // row-sum partials: combine the 4 lanes sharing l15
  ksp += __shfl_xor(ksp, 16);
  ksp += __shfl_xor(ksp, 32);
  __shared__ float red[4][4][16][16];
  __shared__ float ksred[4][16];
  if (l4 == 0) ksred[wid][l15] = ksp;
  #pragma unroll
  for (int ct=0;ct<4;ct++)
    #pragma unroll
    for (int r=0;r<4;r++) red[wid][ct][l4*4+r][l15] = acc[ct][r];
  __syncthreads();
  #pragma unroll
  for (int i=0;i<4;i++){
    int e = i*256 + t;
    int ct = e>>8, row = (e>>4)&15, col = e&15;
    float s = ((red[0][ct][row][col] + red[1][ct][row][col])
             + (red[2][ct][row][col] + red[3][ct][row][col]));
    ctxP[(((size_t)bhl*8 + ks)*272 + m0 + row)*64 + ct*16 + col] = s;
  }
  if (t < 16){
    float s2 = ksred[0][t] + ksred[1][t] + ksred[2][t] + ksred[3][t];
    ksumP[((size_t)bhl*8 + ks)*272 + m0 + t] = s2;
  }
}

// reduce K-split partials -> ctxT[bh][d][MPAD m] bf16 (zero pad m>=272) and
// ksumf[bh][m].  grid (72, KG)
__global__ __launch_bounds__(256)
void ctx_reduce(const float* __restrict__ ctxP, const float* __restrict__ ksumP,
                bf16_t* __restrict__ ctxT, float* __restrict__ ksumf, int bh0)
{
  int bhl = blockIdx.y, bh = bh0 + bhl;
  int idx = blockIdx.x*256 + threadIdx.x;   // < 18432 = 288*64
  int m = idx>>6, d = idx&63;
  float s = 0.f;
  if (m < 272){
    #pragma unroll
    for (int ks=0;ks<8;ks++)
      s += ctxP[(((size_t)bhl*8 + ks)*272 + m)*64 + d];
  }
  ctxT[((size_t)bh*64 + d)*MPAD + m] = f2b(s);
  if (idx < 272){
    float s2 = 0.f;
    #pragma unroll
    for (int ks=0;ks<8;ks++)
      s2 += ksumP[(((size_t)bhl*8 + ks)*272) + idx];
    ksumf[(size_t)bh*MPAD + idx] = s2;
  }
}

// fused q-side: dd MFMA -> in-kernel diag -> rowmax -> qp -> LDS ->
// out MFMA * dinv -> attn. grid (64, 32), block 256
__global__ __launch_bounds__(256,2)
void favor_q(const bf16_t* __restrict__ qkv, const bf16_t* __restrict__ pmb,
             const float* __restrict__ ksumf,
             const bf16_t* __restrict__ ctxT, bf16_t* __restrict__ attn)
{
  __shared__ alignas(16) ushort qpLds[64*296];
  __shared__ float ksLds[288];
  int bh = blockIdx.y, b = bh>>3, h = bh&7;
  int t = threadIdx.x, wid = t>>6, lane = t&63;
  int l15 = lane&15, l4 = lane>>4;
  int n0 = blockIdx.x*64, row0 = wid*16;
  ksLds[t] = (t < 272) ? ksumf[(size_t)bh*MPAD + t] : 0.f;
  if (t < 32) ksLds[256+t] = (256+t < 272) ? ksumf[(size_t)bh*MPAD + 256 + t] : 0.f;
  __syncthreads();

  f32x4 acc[18];
  #pragma unroll
  for (int c=0;c<18;c++) acc[c] = f32x4{0.f,0.f,0.f,0.f};
  const bf16_t* abase = qkv + ((size_t)(b*4096) + n0 + row0 + l15)*1536 + h*64;
  float rsq = 0.f;
  #pragma unroll
  for (int kh=0;kh<2;kh++){
    bf16x8 a = *(const bf16x8*)(abase + kh*32 + l4*8);
    #pragma unroll
    for (int e=0;e<8;e++){ float v = b2f((bf16_t)a[e]); rsq += v*v; }
    #pragma unroll
    for (int ct=0;ct<18;ct++){
      bf16x8 bb = *(const bf16x8*)(pmb + (ct*16+l15)*64 + kh*32 + l4*8);
      acc[ct] = MFMA16(a, bb, acc[ct]);
    }
  }
  rsq += __shfl_xor(rsq, 16);
  rsq += __shfl_xor(rsq, 32);
  constexpr float DSC = 0.5f*DN_SCALE*DN_SCALE;
  float dg[4];
  #pragma unroll
  for (int r=0;r<4;r++) dg[r] = DSC * __shfl(rsq, l4*4 + r);

  // per-row max over valid cols
  float mxr[4] = {-3e38f,-3e38f,-3e38f,-3e38f};
  #pragma unroll
  for (int ct=0;ct<18;ct++){
    if (ct*16 + l15 < 266){
      #pragma unroll
      for (int r=0;r<4;r++) mxr[r] = fmaxf(mxr[r], acc[ct][r]);
    }
  }
  #pragma unroll
  for (int r=0;r<4;r++){
    mxr[r] = fmaxf(mxr[r], __shfl_xor(mxr[r], 1));
    mxr[r] = fmaxf(mxr[r], __shfl_xor(mxr[r], 2));
    mxr[r] = fmaxf(mxr[r], __shfl_xor(mxr[r], 4));
    mxr[r] = fmaxf(mxr[r], __shfl_xor(mxr[r], 8));
  }
  float den[4] = {0.f,0.f,0.f,0.f};
  #pragma unroll
  for (int ct=0;ct<18;ct++){
    int col = ct*16 + l15;
    float ks = ksLds[col];
    #pragma unroll
    for (int r=0;r<4;r++){
      float qpv = 0.f;
      if (col < 266){
        qpv = RATIO*(__expf(acc[ct][r] - dg[r] - mxr[r]) + KEPS);
        den[r] += qpv*ks;
      }
      qpLds[(row0 + l4*4 + r)*296 + col] = f2b(qpv);
    }
  }
  float dinv[4];
  #pragma unroll
  for (int r=0;r<4;r++){
    den[r] += __shfl_xor(den[r], 1);
    den[r] += __shfl_xor(den[r], 2);
    den[r] += __shfl_xor(den[r], 4);
    den[r] += __shfl_xor(den[r], 8);
    dinv[r] = 1.0f/den[r];
  }
  __syncthreads();

  f32x4 o2[4];
  #pragma unroll
  for (int c=0;c<4;c++) o2[c] = f32x4{0.f,0.f,0.f,0.f};
  const bf16_t* Bbase = ctxT + (size_t)bh*64*MPAD;
  #pragma unroll
  for (int kk=0;kk<9;kk++){
    int k0 = kk*32;
    bf16x8 a = *(const bf16x8*)&qpLds[(row0 + l15)*296 + k0 + l4*8];
    #pragma unroll
    for (int ct=0;ct<4;ct++){
      bf16x8 bb = *(const bf16x8*)(Bbase + (size_t)(ct*16+l15)*MPAD + k0 + l4*8);
      o2[ct] = MFMA16(a, bb, o2[ct]);
    }
  }
  #pragma unroll
  for (int ct=0;ct<4;ct++)
    #pragma unroll
    for (int r=0;r<4;r++)
      attn[((size_t)(b*4096) + n0 + row0 + l4*4 + r)*512 + h*64 + ct*16 + l15]
        = f2b(o2[ct][r] * dinv[r]);
}

// ---------------------------------------------------------------- launcher
extern "C" void kernel_launch(void* const* d_in, const int* in_sizes, int n_in,
                              void* d_out, int out_size, void* d_ws, size_t ws_size,
                              hipStream_t stream)
{
  (void)in_sizes; (void)n_in; (void)out_size;
  const float* x      = (const float*)d_in[0];
  const float* proj_w = (const float*)d_in[1];
  const float* proj_b = (const float*)d_in[2];
  const float* ln1_g  = (const float*)d_in[3];
  const float* ln1_b  = (const float*)d_in[4];
  const float* wq     = (const float*)d_in[5];
  const float* bq     = (const float*)d_in[6];
  const float* wk     = (const float*)d_in[7];
  const float* bk     = (const float*)d_in[8];
  const float* wv     = (const float*)d_in[9];
  const float* bv     = (const float*)d_in[10];
  const float* wo     = (const float*)d_in[11];
  const float* bo     = (const float*)d_in[12];
  const float* pm     = (const float*)d_in[13];
  const float* ln2_g  = (const float*)d_in[14];
  const float* ln2_b  = (const float*)d_in[15];
  const float* w1     = (const float*)d_in[16];
  const float* b1     = (const float*)d_in[17];
  const float* w2     = (const float*)d_in[18];
  const float* b2     = (const float*)d_in[19];
  float* out = (float*)d_out;
  const size_t MB = 1ull<<20;

  char* ws = (char*)d_ws;
  size_t off = 0;
  auto alloc = [&](size_t bytes)->void*{ void* p = ws + off; off += (bytes + 255) & ~(size_t)255; return p; };
  bf16_t* Wt_proj = (bf16_t*)alloc(2ul*1024*1024);
  bf16_t* Wt_qkv  = (bf16_t*)alloc(2ul*1536*1024);
  bf16_t* Wt_o    = (bf16_t*)alloc(2ul*1024*512);
  bf16_t* Wt_1    = (bf16_t*)alloc(2ul*4096*1024);
  bf16_t* Wt_2    = (bf16_t*)alloc(2ul*1024*4096);
  float*  bqkv    = (float*) alloc(4ul*1536);
  unsigned* mxk   = (unsigned*)alloc(4ul*32);
  bf16_t* pmb     = (bf16_t*)alloc(2ul*MPAD*64);
  float*  ksumf   = (float*) alloc(4ul*32*MPAD);
  bf16_t* ctxT    = (bf16_t*)alloc(2ul*32*64*MPAD);
  float*  ctxP    = (float*) alloc(4ul*8*8*272*64);   // K-split partials (KG<=8, ks=8)
  float*  ksumP   = (float*) alloc(4ul*8*8*272);
  char*   R       = (char*)  alloc(0);
  size_t R_avail = (ws_size > off) ? ws_size - off : 0;

  // region floor: phase A 64MB, k-side KG=4 ~58MB, ff NC=4 50MB
  if (R_avail < 67*MB){ zero_out<<<dim3(65536), 256, 0, stream>>>(out, 16777216L); return; }
  int KG = (R_avail >= 87*MB) ? 8 : 4;    // k-side top: 48 + KG*2.36MB
  int NC = (R_avail >= 84*MB) ? 2 : 4;    // ff top: 16 + (16384/NC)*8KB

  // R overlays (stream-serialized disjoint lifetimes)
  bf16_t* qkv  = (bf16_t*)(R);               // 48MB   [LN1/qkv .. favor_q]
  bf16_t* h1c  = (bf16_t*)(R + 48*MB);       // 16MB   [phase A]
  bf16_t* kpT  = (bf16_t*)(R + 48*MB);       // KG*2.36MB [k-side]
  bf16_t* attn = (bf16_t*)(R + 48*MB);       // 16MB   [favor_q .. wo]
  long    CH   = 16384/NC;
  bf16_t* h2c  = (bf16_t*)(R);               // reused as xbc too
  bf16_t* ff1c = (bf16_t*)(R + 16*MB);       // CH*8KB
  bf16_t* vT   = (bf16_t*)d_out;             // 16.8MB scratch in d_out (dead till wo)

  // 1) weights -> bf16 transposed, pm cast
  wt_cast<<<dim3(32,32), 256, 0, stream>>>(proj_w, Wt_proj, 1024, 1024);
  wt_cast<<<dim3(32,16), 256, 0, stream>>>(wq, Wt_qkv,              1024, 512);
  wt_cast<<<dim3(32,16), 256, 0, stream>>>(wk, Wt_qkv + 512*1024,   1024, 512);
  wt_cast<<<dim3(32,16), 256, 0, stream>>>(wv, Wt_qkv + 1024*1024,  1024, 512);
  wt_cast<<<dim3(16,32), 256, 0, stream>>>(wo, Wt_o, 512, 1024);
  wt_cast<<<dim3(32,128),256, 0, stream>>>(w1, Wt_1, 1024, 4096);
  wt_cast<<<dim3(128,32),256, 0, stream>>>(w2, Wt_2, 4096, 1024);
  concat_bias<<<dim3(6), 256, 0, stream>>>(bq, bk, bv, bqkv);
  pm_cast<<<dim3(72), 256, 0, stream>>>(pm, pmb);

  // 2) phase A: LN1 + qkv GEMM, 2 chunks of 8192 rows (L2-resident staging)
  for (int c = 0; c < 2; c++){
    ln_kernel<<<dim3(8192), 256, 0, stream>>>(x + (size_t)c*8192*1024, ln1_g, ln1_b, h1c);
    gemm_bt<0,0,0,1><<<dim3(12,64), 256, 0, stream>>>(h1c, 1024, Wt_qkv, 1024,
        bqkv, nullptr, nullptr, qkv + (size_t)c*8192*1536, 1536, 1024);
  }

  // 3) FAVOR
  vt_trans<<<dim3(128,64), 256, 0, stream>>>(qkv, vT);
  mx_init<<<dim3(1), 64, 0, stream>>>(mxk);
  favor_kmax2<<<dim3(64,32), 256, 0, stream>>>(qkv, pmb, mxk);
  for (int g = 0; g < 32; g += KG){
    favor_kp<<<dim3(64,KG), 256, 0, stream>>>(qkv, pmb, mxk, kpT, g);
    ctx_gemm<<<dim3(17,8,KG), 256, 0, stream>>>(kpT, vT, ctxP, ksumP, g);
    ctx_reduce<<<dim3(72,KG), 256, 0, stream>>>(ctxP, ksumP, ctxT, ksumf, g);
  }
  favor_q<<<dim3(64,32), 256, 0, stream>>>(qkv, pmb, ksumf, ctxT, attn);

  // 4) x2 = x + attn @ wo + bo -> d_out (f32); overwrites vT scratch
  gemm_bt<1,0,0,0><<<dim3(8,128), 256, 0, stream>>>(attn, 512, Wt_o, 512,
      bo, x, nullptr, out, 1024, 512);

  // 5) per chunk: LN2 -> ff1(gelu) -> ff2(+res, in-place) -> gate(in-place)
  for (int c = 0; c < NC; c++){
    float* xrow = out + (size_t)c*CH*1024;
    ln_kernel<<<dim3((unsigned)CH), 256, 0, stream>>>(xrow, ln2_g, ln2_b, h2c);
    gemm_bt<0,1,0,1><<<dim3(32,(unsigned)(CH/128)), 256, 0, stream>>>(h2c, 1024, Wt_1, 1024,
        b1, nullptr, nullptr, ff1c, 4096, 1024);
    gemm_bt<1,0,0,0><<<dim3(8,(unsigned)(CH/128)), 256, 0, stream>>>(ff1c, 4096, Wt_2, 4096,
        b2, xrow, nullptr, xrow, 1024, 4096);
    cast_f32_bf16<<<dim3((unsigned)CH), 256, 0, stream>>>(x + (size_t)c*CH*1024, h2c);
    gemm_bt<0,0,1,0><<<dim3(8,(unsigned)(CH/128)), 256, 0, stream>>>(h2c, 1024, Wt_proj, 1024,
        proj_b, nullptr, xrow, xrow, 1024, 1024);
  }
}

// Round 16
// 907.112 us; speedup vs baseline: 1.1195x; 1.0185x over previous
//
#include <hip/hip_runtime.h>
#include <math.h>

typedef unsigned short bf16_t;
using bf16x8 = __attribute__((ext_vector_type(8))) short;
using f32x4  = __attribute__((ext_vector_type(4))) float;

#define DEVFN static __device__ __forceinline__

DEVFN float b2f(bf16_t u){ unsigned v=((unsigned)u)<<16; float f; __builtin_memcpy(&f,&v,4); return f; }
DEVFN bf16_t f2b(float f){ unsigned u; __builtin_memcpy(&u,&f,4); u += 0x7fffu + ((u>>16)&1u); return (bf16_t)(u>>16); }
DEVFN unsigned encf(float f){ unsigned u=__float_as_uint(f); return (u&0x80000000u)? ~u : (u|0x80000000u); }
DEVFN float decf(unsigned e){ return __uint_as_float((e&0x80000000u)? (e^0x80000000u) : ~e); }

// erf via Abramowitz-Stegun 7.1.26, |abs err| <= 1.5e-7
DEVFN float erf_fast(float x){
  float ax = fabsf(x);
  float t = __builtin_amdgcn_rcpf(1.0f + 0.3275911f*ax);
  float y = t*(0.254829592f + t*(-0.284496736f + t*(1.421413741f
          + t*(-1.453152027f + t*1.061405429f))));
  float r = 1.0f - y*__expf(-ax*ax);
  return copysignf(r, x);
}

constexpr float DN_SCALE = 0.35355339059327373f;   // 64^-0.25
constexpr float RATIO    = 0.06131393394849658f;   // 266^-0.5
constexpr float KEPS     = 1e-4f;
#define MPAD 288   // 266 features padded to 9*32

#define GLOAD_LDS16(g, l) __builtin_amdgcn_global_load_lds( \
    (__attribute__((address_space(1))) void*)(g), \
    (__attribute__((address_space(3))) void*)(l), 16, 0, 0)

#define MFMA16(a,b,c) __builtin_amdgcn_mfma_f32_16x16x32_bf16(a,b,c,0,0,0)

// ------------------------------------------------ fused weight transpose+cast
// 7 weight matrices in one launch; per-segment W [K][N] f32 -> Wt [N][K] bf16.
// block ranges: [0,1024) proj | [1024,1536) wq | [1536,2048) wk |
// [2048,2560) wv | [2560,3072) wo | [3072,7168) w1 | [7168,11264) w2
__global__ __launch_bounds__(256)
void wt_cast_all(const float* __restrict__ proj_w, const float* __restrict__ wq,
                 const float* __restrict__ wk, const float* __restrict__ wv,
                 const float* __restrict__ wo, const float* __restrict__ w1,
                 const float* __restrict__ w2,
                 bf16_t* __restrict__ Wt_proj, bf16_t* __restrict__ Wt_qkv,
                 bf16_t* __restrict__ Wt_o, bf16_t* __restrict__ Wt_1,
                 bf16_t* __restrict__ Wt_2)
{
  __shared__ alignas(16) float ts[32][33];
  int bid = blockIdx.x;
  const float* W; bf16_t* Wt; int K, N, bx, by;
  if      (bid < 1024){ int r=bid;      W=proj_w; Wt=Wt_proj;           K=1024; N=1024; bx=r&31;  by=r>>5; }
  else if (bid < 1536){ int r=bid-1024; W=wq;     Wt=Wt_qkv;            K=1024; N=512;  bx=r&31;  by=r>>5; }
  else if (bid < 2048){ int r=bid-1536; W=wk;     Wt=Wt_qkv+512*1024;   K=1024; N=512;  bx=r&31;  by=r>>5; }
  else if (bid < 2560){ int r=bid-2048; W=wv;     Wt=Wt_qkv+1024*1024;  K=1024; N=512;  bx=r&31;  by=r>>5; }
  else if (bid < 3072){ int r=bid-2560; W=wo;     Wt=Wt_o;              K=512;  N=1024; bx=r&15;  by=r>>4; }
  else if (bid < 7168){ int r=bid-3072; W=w1;     Wt=Wt_1;              K=1024; N=4096; bx=r&31;  by=r>>5; }
  else               { int r=bid-7168; W=w2;     Wt=Wt_2;              K=4096; N=1024; bx=r&127; by=r>>7; }
  int t = threadIdx.x;
  int r = t>>3, c4 = (t&7)*4;
  int k0 = bx*32, n0 = by*32;
  float4 v = *(const float4*)(W + (size_t)(k0+r)*N + n0 + c4);
  ts[r][c4+0]=v.x; ts[r][c4+1]=v.y; ts[r][c4+2]=v.z; ts[r][c4+3]=v.w;
  __syncthreads();
  ushort4 o;
  o.x = f2b(ts[c4+0][r]); o.y = f2b(ts[c4+1][r]);
  o.z = f2b(ts[c4+2][r]); o.w = f2b(ts[c4+3][r]);
  *(ushort4*)(Wt + (size_t)(n0+r)*K + k0 + c4) = o;
}

// fused tiny prologue: pmb cast (blocks 0..71), bias concat (72..77), mxk (72)
__global__ __launch_bounds__(256)
void prologue_small(const float* __restrict__ bq, const float* __restrict__ bk,
                    const float* __restrict__ bv, float* __restrict__ bqkv,
                    const float* __restrict__ pm, bf16_t* __restrict__ pmb,
                    unsigned* __restrict__ mxk)
{
  int bid = blockIdx.x, t = threadIdx.x;
  if (bid < 72){
    int idx = bid*256 + t;
    int r = idx>>6, c = idx&63;
    pmb[idx] = (r < 266) ? f2b(pm[r*64+c]*DN_SCALE) : (bf16_t)0;
  } else {
    int j = (bid-72)*256 + t;
    if (j < 512) bqkv[j] = bq[j];
    else if (j < 1024) bqkv[j] = bk[j-512];
    else bqkv[j] = bv[j-1024];
    if (bid == 72 && t < 32) mxk[t] = 0u;
  }
}

__global__ void zero_out(float* o, long n){
  long i = (long)blockIdx.x*256 + threadIdx.x;
  if (i < n) o[i] = 0.f;
}

// v transpose: qkv v-part -> vT[bh*64+d][4096]. grid (128, 64), block 256
__global__ __launch_bounds__(256)
void vt_trans(const bf16_t* __restrict__ qkv, bf16_t* __restrict__ vT)
{
  __shared__ ushort ts[32][36];
  int by = blockIdx.y;
  int bh = by>>1, dt = by&1, b = bh>>3, h = bh&7;
  int n0 = blockIdx.x*32;
  int t = threadIdx.x, r = t>>3, c4 = (t&7)*4;
  ushort4 v = *(const ushort4*)(qkv + ((size_t)b*4096 + n0 + r)*1536 + 1024 + h*64 + dt*32 + c4);
  ts[r][c4+0]=v.x; ts[r][c4+1]=v.y; ts[r][c4+2]=v.z; ts[r][c4+3]=v.w;
  __syncthreads();
  ushort4 o;
  o.x = ts[c4+0][r]; o.y = ts[c4+1][r]; o.z = ts[c4+2][r]; o.w = ts[c4+3][r];
  *(ushort4*)(vT + ((size_t)bh*64 + dt*32 + r)*4096 + n0 + c4) = o;
}

// ---------------------------------------------------------------- LayerNorm
__global__ __launch_bounds__(256)
void ln_kernel(const float* __restrict__ x, const float* __restrict__ g,
               const float* __restrict__ b, bf16_t* __restrict__ out)
{
  long row = blockIdx.x; int t = threadIdx.x;
  float4 v = ((const float4*)x)[row*256 + t];
  float s = v.x+v.y+v.z+v.w;
  #pragma unroll
  for (int o=32;o>0;o>>=1) s += __shfl_xor(s, o);
  __shared__ float r1[4], r2[4];
  if ((t&63)==0) r1[t>>6] = s;
  __syncthreads();
  float mu = (r1[0]+r1[1]+r1[2]+r1[3]) * (1.f/1024.f);
  float dx = v.x-mu, dy = v.y-mu, dz = v.z-mu, dw = v.w-mu;
  float ss = dx*dx+dy*dy+dz*dz+dw*dw;
  #pragma unroll
  for (int o=32;o>0;o>>=1) ss += __shfl_xor(ss, o);
  if ((t&63)==0) r2[t>>6] = ss;
  __syncthreads();
  float var = (r2[0]+r2[1]+r2[2]+r2[3]) * (1.f/1024.f);
  float rs = rsqrtf(var + 1e-5f);
  float4 gg = ((const float4*)g)[t], bb = ((const float4*)b)[t];
  ushort4 o4;
  o4.x = f2b(dx*rs*gg.x+bb.x); o4.y = f2b(dy*rs*gg.y+bb.y);
  o4.z = f2b(dz*rs*gg.z+bb.z); o4.w = f2b(dw*rs*gg.w+bb.w);
  ((ushort4*)out)[row*256+t] = o4;
}

// f32 -> bf16 cast, grid = rows (of 1024)
__global__ __launch_bounds__(256)
void cast_f32_bf16(const float* __restrict__ in, bf16_t* __restrict__ out)
{
  long i = (long)blockIdx.x*256 + threadIdx.x;
  float4 v = ((const float4*)in)[i];
  ushort4 o;
  o.x = f2b(v.x); o.y = f2b(v.y); o.z = f2b(v.z); o.w = f2b(v.w);
  ((ushort4*)out)[i] = o;
}

// ---------------------------------------------------------------- GEMM (bf16 MFMA)
// 128x128 tile, BK=32, 4 waves, double-buffered LDS (2-phase: stage tile t+1
// BEFORE computing tile t; one __syncthreads per step).  PROVEN OPTIMUM here:
// manual vmcnt/raw-barrier variants all measured slower (R6/R8/R10); larger
// staging chunks break L2 residency (R12).  XCD-bijective chunking +
// 16-row supertile block remap for L2 locality (requires nwg%8==0, Mtiles%16==0).
template<int RES, int GELU, int GATEF, int OBF>
__global__ __launch_bounds__(256)
void gemm_bt(const bf16_t* __restrict__ A, int lda,
             const bf16_t* __restrict__ Bt, int ldb,
             const float* __restrict__ bias,
             const float* res,
             const float* gatef,
             void* Cout, int N, int K)
{
  __shared__ alignas(16) bf16_t As[2][128*32];
  __shared__ alignas(16) bf16_t Bs[2][128*32];
  const int tid = threadIdx.x;
  const int wid = tid>>6, lane = tid&63;
  const int l15 = lane&15, l4 = lane>>4;
  const int wm = wid>>1, wn = wid&1;

  // ---- block remap: XCD-contiguous chunks over a ty-fast supertiled order
  const int NX = gridDim.x;
  const int nwg = NX * gridDim.y;
  const int lid = blockIdx.y*NX + blockIdx.x;
  const int qc = nwg>>3;
  const int wgid = (lid&7)*qc + (lid>>3);          // nwg%8==0 bijective chunk
  const int stripe = wgid / (16*NX);
  const int rem    = wgid % (16*NX);
  const long m0 = (long)(stripe*16 + (rem & 15))*128;
  const long n0 = (long)(rem >> 4)*128;

  f32x4 acc[4][4];
  #pragma unroll
  for (int i=0;i<4;i++)
    #pragma unroll
    for (int j=0;j<4;j++) acc[i][j] = f32x4{0.f,0.f,0.f,0.f};

  const bf16_t* ga = A  + (size_t)(m0 + (tid>>2))*lda + (tid&3)*8;
  const bf16_t* gb = Bt + (size_t)(n0 + (tid>>2))*ldb + (tid&3)*8;

  auto STAGE = [&](int buf){
    GLOAD_LDS16(ga,                   &As[buf][wid*512]);
    GLOAD_LDS16(ga + (size_t)64*lda,  &As[buf][2048 + wid*512]);
    GLOAD_LDS16(gb,                   &Bs[buf][wid*512]);
    GLOAD_LDS16(gb + (size_t)64*ldb,  &Bs[buf][2048 + wid*512]);
    ga += 32; gb += 32;
  };

  const int nt = K >> 5;
  STAGE(0);
  __syncthreads();                      // drains vmcnt(0): tile 0 resident
  int cur = 0;
  for (int t = 0; t < nt; ++t){
    if (t+1 < nt) STAGE(cur^1);         // issue next-tile loads FIRST
    bf16x8 af[4], bfr[4];
    #pragma unroll
    for (int i=0;i<4;i++){
      af[i]  = *(const bf16x8*)(&As[cur][(wm*64 + i*16 + l15)*32 + l4*8]);
      bfr[i] = *(const bf16x8*)(&Bs[cur][(wn*64 + i*16 + l15)*32 + l4*8]);
    }
    #pragma unroll
    for (int i=0;i<4;i++)
      #pragma unroll
      for (int j=0;j<4;j++)
        acc[i][j] = MFMA16(af[i], bfr[j], acc[i][j]);
    __syncthreads();                    // drains vmcnt(0): next tile resident,
    cur ^= 1;                           // and all reads of As[cur] complete
  }

  #pragma unroll
  for (int i=0;i<4;i++){
    #pragma unroll
    for (int j=0;j<4;j++){
      #pragma unroll
      for (int r=0;r<4;r++){
        long row = m0 + wm*64 + i*16 + l4*4 + r;
        long col = n0 + wn*64 + j*16 + l15;
        float v = acc[i][j][r] + bias[col];
        if constexpr (RES)   v += res[row*(long)N + col];
        if constexpr (GELU)  v = 0.5f*v*(1.0f + erf_fast(v*0.70710678118654752f));
        if constexpr (GATEF) v *= gatef[row*(long)N + col];
        if constexpr (OBF)  ((bf16_t*)Cout)[row*(long)N + col] = f2b(v);
        else                ((float* )Cout)[row*(long)N + col] = v;
      }
    }
  }
}

// ---------------------------------------------------------------- FAVOR (MFMA)
// qkv: [16384][1536] bf16, q @ h*64, k @ 512+h*64, v @ 1024+h*64.

// dd-max over all (n,m) per bh. grid (64, 32), block 256 (4 waves x 16 rows)
__global__ __launch_bounds__(256,2)
void favor_kmax2(const bf16_t* __restrict__ qkv, const bf16_t* __restrict__ pmb,
                 unsigned* __restrict__ mxk)
{
  int bh = blockIdx.y, b = bh>>3, h = bh&7;
  int t = threadIdx.x, wid = t>>6, lane = t&63;
  int l15 = lane&15, l4 = lane>>4;
  int n0 = blockIdx.x*64, row0 = wid*16;
  f32x4 acc[18];
  #pragma unroll
  for (int c=0;c<18;c++) acc[c] = f32x4{0.f,0.f,0.f,0.f};
  const bf16_t* abase = qkv + ((size_t)(b*4096) + n0 + row0 + l15)*1536 + 512 + h*64;
  #pragma unroll
  for (int kh=0;kh<2;kh++){
    bf16x8 a = *(const bf16x8*)(abase + kh*32 + l4*8);
    #pragma unroll
    for (int ct=0;ct<18;ct++){
      bf16x8 bb = *(const bf16x8*)(pmb + (ct*16+l15)*64 + kh*32 + l4*8);
      acc[ct] = MFMA16(a, bb, acc[ct]);
    }
  }
  float mx = -3e38f;
  #pragma unroll
  for (int ct=0;ct<18;ct++){
    if (ct*16 + l15 < 266){
      #pragma unroll
      for (int r=0;r<4;r++) mx = fmaxf(mx, acc[ct][r]);
    }
  }
  #pragma unroll
  for (int o=32;o>0;o>>=1) mx = fmaxf(mx, __shfl_xor(mx, o));
  __shared__ float red[4];
  if (lane==0) red[wid] = mx;
  __syncthreads();
  if (t==0){
    float m2 = fmaxf(fmaxf(red[0],red[1]),fmaxf(red[2],red[3]));
    atomicMax(mxk + bh, encf(m2));
  }
}

// kp = ratio*(exp(dd - diag - MX)+eps) -> kpT[bhl][MPAD m][4096 n], staged
// through LDS for coalesced 128B row-segment writes.  grid (64, KG), block 256
__global__ __launch_bounds__(256,2)
void favor_kp(const bf16_t* __restrict__ qkv, const bf16_t* __restrict__ pmb,
              const unsigned* __restrict__ mxk, bf16_t* __restrict__ kpT, int bh0)
{
  __shared__ ushort ts[288][68];   // [m][n-local], +4 pad: 2-way max bank alias
  int bhl = blockIdx.y, bh = bh0 + bhl, b = bh>>3, h = bh&7;
  int t = threadIdx.x, wid = t>>6, lane = t&63;
  int l15 = lane&15, l4 = lane>>4;
  int n0 = blockIdx.x*64, row0 = wid*16;
  f32x4 acc[18];
  #pragma unroll
  for (int c=0;c<18;c++) acc[c] = f32x4{0.f,0.f,0.f,0.f};
  const bf16_t* abase = qkv + ((size_t)(b*4096) + n0 + row0 + l15)*1536 + 512 + h*64;
  float rsq = 0.f;
  #pragma unroll
  for (int kh=0;kh<2;kh++){
    bf16x8 a = *(const bf16x8*)(abase + kh*32 + l4*8);
    #pragma unroll
    for (int e=0;e<8;e++){ float v = b2f((bf16_t)a[e]); rsq += v*v; }
    #pragma unroll
    for (int ct=0;ct<18;ct++){
      bf16x8 bb = *(const bf16x8*)(pmb + (ct*16+l15)*64 + kh*32 + l4*8);
      acc[ct] = MFMA16(a, bb, acc[ct]);
    }
  }
  rsq += __shfl_xor(rsq, 16);
  rsq += __shfl_xor(rsq, 32);                 // lanes sharing l15: full row sumsq
  float MX = decf(mxk[bh]);
  constexpr float DSC = 0.5f*DN_SCALE*DN_SCALE;
  float dg[4];
  #pragma unroll
  for (int r=0;r<4;r++) dg[r] = DSC * __shfl(rsq, l4*4 + r);
  #pragma unroll
  for (int ct=0;ct<18;ct++){
    int col = ct*16 + l15;
    ushort4 o;
    if (col < 266){
      o.x = f2b(RATIO*(__expf(acc[ct][0] - dg[0] - MX) + KEPS));
      o.y = f2b(RATIO*(__expf(acc[ct][1] - dg[1] - MX) + KEPS));
      o.z = f2b(RATIO*(__expf(acc[ct][2] - dg[2] - MX) + KEPS));
      o.w = f2b(RATIO*(__expf(acc[ct][3] - dg[3] - MX) + KEPS));
    } else { o.x=0; o.y=0; o.z=0; o.w=0; }
    *(ushort4*)&ts[col][row0 + l4*4] = o;
  }
  __syncthreads();
  // write-out: 8 lanes x 16B = coalesced 128B per m-row; 32 rows/iter x 9
  int lr = lane>>3, cc = lane&7;
  #pragma unroll
  for (int it=0; it<9; ++it){
    int m = it*32 + wid*8 + lr;
    ushort4 w0 = *(ushort4*)&ts[m][cc*8];
    ushort4 w1 = *(ushort4*)&ts[m][cc*8+4];
    bf16_t* dst = kpT + ((size_t)bhl*MPAD + m)*4096 + n0 + cc*8;
    *(ushort4*)(dst)   = w0;
    *(ushort4*)(dst+4) = w1;
  }
}

// ctx partial GEMM (K-split x8 for occupancy) with fused partial ksum.
// grid (17, 8, KG), block 256
__global__ __launch_bounds__(256,2)
void ctx_gemm(const bf16_t* __restrict__ kpT, const bf16_t* __restrict__ vT,
              float* __restrict__ ctxP, float* __restrict__ ksumP, int bh0)
{
  int m0 = blockIdx.x*16, ks = blockIdx.y, bhl = blockIdx.z, bh = bh0 + bhl;
  int t = threadIdx.x, wid = t>>6, lane = t&63;
  int l15 = lane&15, l4 = lane>>4;
  f32x4 acc[4];
  #pragma unroll
  for (int c=0;c<4;c++) acc[c] = f32x4{0.f,0.f,0.f,0.f};
  const bf16_t* Abase = kpT + ((size_t)bhl*MPAD + m0 + l15)*4096;
  const bf16_t* Bbase = vT + ((size_t)bh*64)*4096;
  const int kb = ks*512 + wid*128;
  float ksp = 0.f;
  for (int k = kb; k < kb + 128; k += 32){
    bf16x8 a = *(const bf16x8*)(Abase + k + l4*8);
    #pragma unroll
    for (int e=0;e<8;e++) ksp += b2f((bf16_t)a[e]);
    #pragma unroll
    for (int ct=0;ct<4;ct++){
      bf16x8 bb = *(const bf16x8*)(Bbase + (size_t)(ct*16+l15)*4096 + k + l4*8);
      acc[ct] = MFMA16(a, bb, acc[ct]);
    }
  }
  // row-sum partials: combine the 4 lanes sharing l15
  ksp += __shfl_xor(ksp, 16);
  ksp += __shfl_xor(ksp, 32);
  __shared__ float red[4][4][16][16];
  __shared__ float ksred[4][16];
  if (l4 == 0) ksred[wid][l15] = ksp;
  #pragma unroll
  for (int ct=0;ct<4;ct++)
    #pragma unroll
    for (int r=0;r<4;r++) red[wid][ct][l4*4+r][l15] = acc[ct][r];
  __syncthreads();
  #pragma unroll
  for (int i=0;i<4;i++){
    int e = i*256 + t;
    int ct = e>>8, row = (e>>4)&15, col = e&15;
    float s = ((red[0][ct][row][col] + red[1][ct][row][col])
             + (red[2][ct][row][col] + red[3][ct][row][col]));
    ctxP[(((size_t)bhl*8 + ks)*272 + m0 + row)*64 + ct*16 + col] = s;
  }
  if (t < 16){
    float s2 = ksred[0][t] + ksred[1][t] + ksred[2][t] + ksred[3][t];
    ksumP[((size_t)bhl*8 + ks)*272 + m0 + t] = s2;
  }
}

// reduce K-split partials -> ctxT[bh][d][MPAD m] bf16 (zero pad m>=272) and
// ksumf[bh][m].  grid (72, KG)
__global__ __launch_bounds__(256)
void ctx_reduce(const float* __restrict__ ctxP, const float* __restrict__ ksumP,
                bf16_t* __restrict__ ctxT, float* __restrict__ ksumf, int bh0)
{
  int bhl = blockIdx.y, bh = bh0 + bhl;
  int idx = blockIdx.x*256 + threadIdx.x;   // < 18432 = 288*64
  int m = idx>>6, d = idx&63;
  float s = 0.f;
  if (m < 272){
    #pragma unroll
    for (int ks=0;ks<8;ks++)
      s += ctxP[(((size_t)bhl*8 + ks)*272 + m)*64 + d];
  }
  ctxT[((size_t)bh*64 + d)*MPAD + m] = f2b(s);
  if (idx < 272){
    float s2 = 0.f;
    #pragma unroll
    for (int ks=0;ks<8;ks++)
      s2 += ksumP[(((size_t)bhl*8 + ks)*272) + idx];
    ksumf[(size_t)bh*MPAD + idx] = s2;
  }
}

// fused q-side: dd MFMA -> in-kernel diag -> rowmax -> qp -> LDS ->
// out MFMA * dinv -> attn. grid (64, 32), block 256
__global__ __launch_bounds__(256,2)
void favor_q(const bf16_t* __restrict__ qkv, const bf16_t* __restrict__ pmb,
             const float* __restrict__ ksumf,
             const bf16_t* __restrict__ ctxT, bf16_t* __restrict__ attn)
{
  __shared__ alignas(16) ushort qpLds[64*296];
  __shared__ float ksLds[288];
  int bh = blockIdx.y, b = bh>>3, h = bh&7;
  int t = threadIdx.x, wid = t>>6, lane = t&63;
  int l15 = lane&15, l4 = lane>>4;
  int n0 = blockIdx.x*64, row0 = wid*16;
  ksLds[t] = (t < 272) ? ksumf[(size_t)bh*MPAD + t] : 0.f;
  if (t < 32) ksLds[256+t] = (256+t < 272) ? ksumf[(size_t)bh*MPAD + 256 + t] : 0.f;
  __syncthreads();

  f32x4 acc[18];
  #pragma unroll
  for (int c=0;c<18;c++) acc[c] = f32x4{0.f,0.f,0.f,0.f};
  const bf16_t* abase = qkv + ((size_t)(b*4096) + n0 + row0 + l15)*1536 + h*64;
  float rsq = 0.f;
  #pragma unroll
  for (int kh=0;kh<2;kh++){
    bf16x8 a = *(const bf16x8*)(abase + kh*32 + l4*8);
    #pragma unroll
    for (int e=0;e<8;e++){ float v = b2f((bf16_t)a[e]); rsq += v*v; }
    #pragma unroll
    for (int ct=0;ct<18;ct++){
      bf16x8 bb = *(const bf16x8*)(pmb + (ct*16+l15)*64 + kh*32 + l4*8);
      acc[ct] = MFMA16(a, bb, acc[ct]);
    }
  }
  rsq += __shfl_xor(rsq, 16);
  rsq += __shfl_xor(rsq, 32);
  constexpr float DSC = 0.5f*DN_SCALE*DN_SCALE;
  float dg[4];
  #pragma unroll
  for (int r=0;r<4;r++) dg[r] = DSC * __shfl(rsq, l4*4 + r);

  // per-row max over valid cols
  float mxr[4] = {-3e38f,-3e38f,-3e38f,-3e38f};
  #pragma unroll
  for (int ct=0;ct<18;ct++){
    if (ct*16 + l15 < 266){
      #pragma unroll
      for (int r=0;r<4;r++) mxr[r] = fmaxf(mxr[r], acc[ct][r]);
    }
  }
  #pragma unroll
  for (int r=0;r<4;r++){
    mxr[r] = fmaxf(mxr[r], __shfl_xor(mxr[r], 1));
    mxr[r] = fmaxf(mxr[r], __shfl_xor(mxr[r], 2));
    mxr[r] = fmaxf(mxr[r], __shfl_xor(mxr[r], 4));
    mxr[r] = fmaxf(mxr[r], __shfl_xor(mxr[r], 8));
  }
  float den[4] = {0.f,0.f,0.f,0.f};
  #pragma unroll
  for (int ct=0;ct<18;ct++){
    int col = ct*16 + l15;
    float ks = ksLds[col];
    #pragma unroll
    for (int r=0;r<4;r++){
      float qpv = 0.f;
      if (col < 266){
        qpv = RATIO*(__expf(acc[ct][r] - dg[r] - mxr[r]) + KEPS);
        den[r] += qpv*ks;
      }
      qpLds[(row0 + l4*4 + r)*296 + col] = f2b(qpv);
    }
  }
  float dinv[4];
  #pragma unroll
  for (int r=0;r<4;r++){
    den[r] += __shfl_xor(den[r], 1);
    den[r] += __shfl_xor(den[r], 2);
    den[r] += __shfl_xor(den[r], 4);
    den[r] += __shfl_xor(den[r], 8);
    dinv[r] = 1.0f/den[r];
  }
  __syncthreads();

  f32x4 o2[4];
  #pragma unroll
  for (int c=0;c<4;c++) o2[c] = f32x4{0.f,0.f,0.f,0.f};
  const bf16_t* Bbase = ctxT + (size_t)bh*64*MPAD;
  #pragma unroll
  for (int kk=0;kk<9;kk++){
    int k0 = kk*32;
    bf16x8 a = *(const bf16x8*)&qpLds[(row0 + l15)*296 + k0 + l4*8];
    #pragma unroll
    for (int ct=0;ct<4;ct++){
      bf16x8 bb = *(const bf16x8*)(Bbase + (size_t)(ct*16+l15)*MPAD + k0 + l4*8);
      o2[ct] = MFMA16(a, bb, o2[ct]);
    }
  }
  #pragma unroll
  for (int ct=0;ct<4;ct++)
    #pragma unroll
    for (int r=0;r<4;r++)
      attn[((size_t)(b*4096) + n0 + row0 + l4*4 + r)*512 + h*64 + ct*16 + l15]
        = f2b(o2[ct][r] * dinv[r]);
}

// ---------------------------------------------------------------- launcher
extern "C" void kernel_launch(void* const* d_in, const int* in_sizes, int n_in,
                              void* d_out, int out_size, void* d_ws, size_t ws_size,
                              hipStream_t stream)
{
  (void)in_sizes; (void)n_in; (void)out_size;
  const float* x      = (const float*)d_in[0];
  const float* proj_w = (const float*)d_in[1];
  const float* proj_b = (const float*)d_in[2];
  const float* ln1_g  = (const float*)d_in[3];
  const float* ln1_b  = (const float*)d_in[4];
  const float* wq     = (const float*)d_in[5];
  const float* bq     = (const float*)d_in[6];
  const float* wk     = (const float*)d_in[7];
  const float* bk     = (const float*)d_in[8];
  const float* wv     = (const float*)d_in[9];
  const float* bv     = (const float*)d_in[10];
  const float* wo     = (const float*)d_in[11];
  const float* bo     = (const float*)d_in[12];
  const float* pm     = (const float*)d_in[13];
  const float* ln2_g  = (const float*)d_in[14];
  const float* ln2_b  = (const float*)d_in[15];
  const float* w1     = (const float*)d_in[16];
  const float* b1     = (const float*)d_in[17];
  const float* w2     = (const float*)d_in[18];
  const float* b2     = (const float*)d_in[19];
  float* out = (float*)d_out;
  const size_t MB = 1ull<<20;

  char* ws = (char*)d_ws;
  size_t off = 0;
  auto alloc = [&](size_t bytes)->void*{ void* p = ws + off; off += (bytes + 255) & ~(size_t)255; return p; };
  bf16_t* Wt_proj = (bf16_t*)alloc(2ul*1024*1024);
  bf16_t* Wt_qkv  = (bf16_t*)alloc(2ul*1536*1024);
  bf16_t* Wt_o    = (bf16_t*)alloc(2ul*1024*512);
  bf16_t* Wt_1    = (bf16_t*)alloc(2ul*4096*1024);
  bf16_t* Wt_2    = (bf16_t*)alloc(2ul*1024*4096);
  float*  bqkv    = (float*) alloc(4ul*1536);
  unsigned* mxk   = (unsigned*)alloc(4ul*32);
  bf16_t* pmb     = (bf16_t*)alloc(2ul*MPAD*64);
  float*  ksumf   = (float*) alloc(4ul*32*MPAD);
  bf16_t* ctxT    = (bf16_t*)alloc(2ul*32*64*MPAD);
  float*  ctxP    = (float*) alloc(4ul*8*8*272*64);   // K-split partials (KG<=8, ks=8)
  float*  ksumP   = (float*) alloc(4ul*8*8*272);
  char*   R       = (char*)  alloc(0);
  size_t R_avail = (ws_size > off) ? ws_size - off : 0;

  // region floor: phase A 64MB, k-side KG=4 ~58MB, ff NC=4 50MB
  if (R_avail < 67*MB){ zero_out<<<dim3(65536), 256, 0, stream>>>(out, 16777216L); return; }
  int KG = (R_avail >= 87*MB) ? 8 : 4;    // k-side top: 48 + KG*2.36MB
  int NC = (R_avail >= 84*MB) ? 2 : 4;    // ff top: 16 + (16384/NC)*8KB

  // R overlays (stream-serialized disjoint lifetimes)
  bf16_t* qkv  = (bf16_t*)(R);               // 48MB   [LN1/qkv .. favor_q]
  bf16_t* h1c  = (bf16_t*)(R + 48*MB);       // 16MB   [phase A]
  bf16_t* kpT  = (bf16_t*)(R + 48*MB);       // KG*2.36MB [k-side]
  bf16_t* attn = (bf16_t*)(R + 48*MB);       // 16MB   [favor_q .. wo]
  long    CH   = 16384/NC;
  bf16_t* h2c  = (bf16_t*)(R);               // reused as xbc too
  bf16_t* ff1c = (bf16_t*)(R + 16*MB);       // CH*8KB
  bf16_t* vT   = (bf16_t*)d_out;             // 16.8MB scratch in d_out (dead till wo)

  // 1) fused prologue: all weight transposes in one launch + tiny setup
  wt_cast_all<<<dim3(11264), 256, 0, stream>>>(proj_w, wq, wk, wv, wo, w1, w2,
      Wt_proj, Wt_qkv, Wt_o, Wt_1, Wt_2);
  prologue_small<<<dim3(78), 256, 0, stream>>>(bq, bk, bv, bqkv, pm, pmb, mxk);

  // 2) phase A: LN1 + qkv GEMM, 2 chunks of 8192 rows (L2-resident staging)
  for (int c = 0; c < 2; c++){
    ln_kernel<<<dim3(8192), 256, 0, stream>>>(x + (size_t)c*8192*1024, ln1_g, ln1_b, h1c);
    gemm_bt<0,0,0,1><<<dim3(12,64), 256, 0, stream>>>(h1c, 1024, Wt_qkv, 1024,
        bqkv, nullptr, nullptr, qkv + (size_t)c*8192*1536, 1536, 1024);
  }

  // 3) FAVOR
  vt_trans<<<dim3(128,64), 256, 0, stream>>>(qkv, vT);
  favor_kmax2<<<dim3(64,32), 256, 0, stream>>>(qkv, pmb, mxk);
  for (int g = 0; g < 32; g += KG){
    favor_kp<<<dim3(64,KG), 256, 0, stream>>>(qkv, pmb, mxk, kpT, g);
    ctx_gemm<<<dim3(17,8,KG), 256, 0, stream>>>(kpT, vT, ctxP, ksumP, g);
    ctx_reduce<<<dim3(72,KG), 256, 0, stream>>>(ctxP, ksumP, ctxT, ksumf, g);
  }
  favor_q<<<dim3(64,32), 256, 0, stream>>>(qkv, pmb, ksumf, ctxT, attn);

  // 4) x2 = x + attn @ wo + bo -> d_out (f32); overwrites vT scratch
  gemm_bt<1,0,0,0><<<dim3(8,128), 256, 0, stream>>>(attn, 512, Wt_o, 512,
      bo, x, nullptr, out, 1024, 512);

  // 5) per chunk: LN2 -> ff1(gelu) -> ff2(+res, in-place) -> gate(in-place)
  for (int c = 0; c < NC; c++){
    float* xrow = out + (size_t)c*CH*1024;
    ln_kernel<<<dim3((unsigned)CH), 256, 0, stream>>>(xrow, ln2_g, ln2_b, h2c);
    gemm_bt<0,1,0,1><<<dim3(32,(unsigned)(CH/128)), 256, 0, stream>>>(h2c, 1024, Wt_1, 1024,
        b1, nullptr, nullptr, ff1c, 4096, 1024);
    gemm_bt<1,0,0,0><<<dim3(8,(unsigned)(CH/128)), 256, 0, stream>>>(ff1c, 4096, Wt_2, 4096,
        b2, xrow, nullptr, xrow, 1024, 4096);
    cast_f32_bf16<<<dim3((unsigned)CH), 256, 0, stream>>>(x + (size_t)c*CH*1024, h2c);
    gemm_bt<0,0,1,0><<<dim3(8,(unsigned)(CH/128)), 256, 0, stream>>>(h2c, 1024, Wt_proj, 1024,
        proj_b, nullptr, xrow, xrow, 1024, 1024);
  }
}